// Round 25
// baseline (492.737 us; speedup 1.0000x reference)
//
#include <hip/hip_runtime.h>
#include <hip/hip_bf16.h>

// FAVOR+ attention, MI355X. Round 25:
//  - mm3_k: y-dim folded into block (grid 1024; y=0..2 loop inside; K-loop
//    head barrier fences cross-y LDS reuse). 12 block-rounds -> 4.
//  - prep_k: convx grid-stride (2048 blocks x 8 iters; grid 3136 total).
//  - outchunk / kvstate / scan / mmo: byte-identical to validated R24.
//
// Workspace (bytes), total 213,942,272 (~204 MB): layout as R17-R24.

#define B_ 4
#define H_ 16
#define L_ 4096
#define D_ 64
#define M_ 256
#define DM_ 1024
#define BH_ 64
#define NSC 32            // superchunks per bh (SC = 128 tokens)

typedef unsigned int u32;
typedef unsigned short u16;
typedef __attribute__((ext_vector_type(8))) short bf16x8;
typedef __attribute__((ext_vector_type(4))) float f32x4;

static __device__ __forceinline__ float bf2f(u16 u) {
  return __uint_as_float(((u32)u) << 16);
}
static __device__ __forceinline__ u16 f2bf(float f) {
  u32 x = __float_as_uint(f);
  return (u16)((x + 0x7fffu + ((x >> 16) & 1u)) >> 16);   // RNE
}
#define MFMA16(a, b, c) __builtin_amdgcn_mfma_f32_16x16x32_bf16((a), (b), (c), 0, 0, 0)
#define LN16 2.772588722239781f

// ---------------- merged prep: convx (grid-stride) | convw | convom --------
__global__ __launch_bounds__(256) void prep_k(
    const float* __restrict__ x, u16* __restrict__ xb,
    const float* __restrict__ W0, const float* __restrict__ W1,
    const float* __restrict__ W2, const float* __restrict__ W3,
    u16* __restrict__ Wt, const float* __restrict__ om,
    u16* __restrict__ omb) {
  __shared__ u16 tt[64][66];
  const int bid = blockIdx.x, tid = threadIdx.x;
  if (bid < 2048) {
    // convx: 4,194,304 float4s, 2048 blocks x 256 thr x 8 iters
#pragma unroll
    for (int s = 0; s < 8; ++s) {
      const int i = (bid * 256 + tid) + s * 524288;
      float4 f = ((const float4*)x)[i];
      ushort4 u;
      u.x = f2bf(f.x); u.y = f2bf(f.y); u.z = f2bf(f.z); u.w = f2bf(f.w);
      ((ushort4*)xb)[i] = u;
    }
  } else if (bid < 3072) {
    const int rem = bid - 2048;
    const int z = rem >> 8, r2 = rem & 255;
    const int k0 = (r2 >> 4) * 64, n0 = (r2 & 15) * 64;
    const float* W = (z == 0) ? W0 : (z == 1) ? W1 : (z == 2) ? W2 : W3;
    u16* o = Wt + (size_t)z * 1048576ull;
    const int r = tid >> 4, c4 = (tid & 15) << 2;
    for (int rr = r; rr < 64; rr += 16) {
      float4 w4 = *(const float4*)(W + (size_t)(k0 + rr) * DM_ + n0 + c4);
      tt[c4 + 0][rr] = f2bf(w4.x);
      tt[c4 + 1][rr] = f2bf(w4.y);
      tt[c4 + 2][rr] = f2bf(w4.z);
      tt[c4 + 3][rr] = f2bf(w4.w);
    }
    __syncthreads();
    for (int rr = r; rr < 64; rr += 16) {
      ushort4 u4;
      u4.x = tt[rr][c4 + 0];
      u4.y = tt[rr][c4 + 1];
      u4.z = tt[rr][c4 + 2];
      u4.w = tt[rr][c4 + 3];
      *(ushort4*)(o + (size_t)(n0 + rr) * DM_ + k0 + c4) = u4;
    }
  } else {
    const int i = (bid - 3072) * 256 + tid;
    omb[i] = f2bf(om[i] * 0.35355339059327373f);     // fold 64^-0.25
  }
}

// ---------------- merged projection GEMMs (q,k,v), y-loop in block ---------
// nh' = 0.0625 * sum(bf2f(f2bf(v))^2) + ln16  (phi scale folded in)
__global__ __launch_bounds__(256) void mm3_k(
    const u16* __restrict__ A, const u16* __restrict__ Wt,
    const float* __restrict__ bq, const float* __restrict__ bk,
    const float* __restrict__ bv, u16* __restrict__ qb,
    u16* __restrict__ kb, u16* __restrict__ vb,
    float* __restrict__ nhq, float* __restrict__ nhk) {
  __shared__ u16 sA[128][64];   // 16 KB, XOR-swizzled 16B slots
  __shared__ u16 sB[128][64];   // 16 KB
  const int tid = threadIdx.x, lane = tid & 63, w = tid >> 6;
  const int fr = lane & 15, fg = lane >> 4;
  const int wr = w >> 1, wc = w & 1;
  const int lb = ((blockIdx.x & 7) << 7) | (blockIdx.x >> 3);
  const int m0 = (lb >> 3) * 128, n0 = (lb & 7) * 128;
  const int srow = tid >> 3, sslot = tid & 7;   // +p*32 rows per pass

#pragma unroll 1
  for (int y = 0; y < 3; ++y) {
    const u16* Bt = Wt + (size_t)y * 1048576ull;
    const float* bias = (y == 0) ? bq : (y == 1) ? bk : bv;
    u16* outp = (y == 0) ? qb : (y == 1) ? kb : vb;
    float* nhout = (y == 0) ? nhq : (y == 1) ? nhk : nullptr;

    f32x4 acc[4][4] = {};
    bf16x8 av[4], bv4[4];
#pragma unroll
    for (int p = 0; p < 4; ++p) {
      av[p]  = *(const bf16x8*)(A  + (size_t)(m0 + srow + p * 32) * DM_ + sslot * 8);
      bv4[p] = *(const bf16x8*)(Bt + (size_t)(n0 + srow + p * 32) * DM_ + sslot * 8);
    }
    for (int k0 = 0; k0 < DM_; k0 += 64) {
      __syncthreads();   // fences prior K-step's (or prior y's) ds_reads
#pragma unroll
      for (int p = 0; p < 4; ++p) {
        const int r = srow + p * 32;
        *(bf16x8*)&sA[r][(sslot ^ (r & 7)) * 8] = av[p];
        *(bf16x8*)&sB[r][(sslot ^ (r & 7)) * 8] = bv4[p];
      }
      if (k0 + 64 < DM_) {
#pragma unroll
        for (int p = 0; p < 4; ++p) {
          av[p]  = *(const bf16x8*)(A  + (size_t)(m0 + srow + p * 32) * DM_ + k0 + 64 + sslot * 8);
          bv4[p] = *(const bf16x8*)(Bt + (size_t)(n0 + srow + p * 32) * DM_ + k0 + 64 + sslot * 8);
        }
      }
      __syncthreads();
#pragma unroll
      for (int ks = 0; ks < 2; ++ks) {
        bf16x8 af[4], bf[4];
#pragma unroll
        for (int i = 0; i < 4; ++i) {
          const int r = wr * 64 + i * 16 + fr;
          af[i] = *(const bf16x8*)&sA[r][((ks * 4 + fg) ^ (r & 7)) * 8];
        }
#pragma unroll
        for (int j = 0; j < 4; ++j) {
          const int r = wc * 64 + j * 16 + fr;
          bf[j] = *(const bf16x8*)&sB[r][((ks * 4 + fg) ^ (r & 7)) * 8];
        }
#pragma unroll
        for (int i = 0; i < 4; ++i)
#pragma unroll
          for (int j = 0; j < 4; ++j)
            acc[i][j] = MFMA16(af[i], bf[j], acc[i][j]);
      }
    }
    const int m_blk = m0 + wr * 64, n_blk = n0 + wc * 64;
    float nhacc[4][4] = {};
#pragma unroll
    for (int j = 0; j < 4; ++j) {
      const int n = n_blk + j * 16 + fr;
      const float bi = bias[n];
      const int h = n >> 6, d = n & 63;
#pragma unroll
      for (int i = 0; i < 4; ++i) {
#pragma unroll
        for (int r = 0; r < 4; ++r) {
          const int m = m_blk + i * 16 + fg * 4 + r;
          const float val = acc[i][j][r] + bi;
          const int b = m >> 12, l = m & 4095;
          const u16 sv = f2bf(val);
          outp[((size_t)(b * H_ + h) * L_ + l) * D_ + d] = sv;
          const float rv = bf2f(sv);
          nhacc[i][r] += rv * rv;
        }
      }
    }
    if (nhout) {
      const int hh2 = n_blk >> 6;
#pragma unroll
      for (int i = 0; i < 4; ++i)
#pragma unroll
        for (int r = 0; r < 4; ++r) {
          float s = nhacc[i][r];
          s += __shfl_xor(s, 1, 64);
          s += __shfl_xor(s, 2, 64);
          s += __shfl_xor(s, 4, 64);
          s += __shfl_xor(s, 8, 64);
          if (fr == 0) {
            const int m = m_blk + i * 16 + fg * 4 + r;
            const int b = m >> 12, l = m & 4095;
            nhout[(size_t)(b * H_ + hh2) * L_ + l] = 0.0625f * s + LN16;
          }
        }
    }
  }
}

// ---------------- final GEMM (attn bf16 -> f32 out), validated -------------
__global__ __launch_bounds__(256) void mmo_k(
    const u16* __restrict__ A, const u16* __restrict__ Bt,
    const float* __restrict__ bias, float* __restrict__ outp) {
  __shared__ u16 sA[128][64];
  __shared__ u16 sB[128][64];
  const int tid = threadIdx.x, lane = tid & 63, w = tid >> 6;
  const int fr = lane & 15, fg = lane >> 4;
  const int wr = w >> 1, wc = w & 1;
  const int lb = ((blockIdx.x & 7) << 7) | (blockIdx.x >> 3);
  const int m0 = (lb >> 3) * 128, n0 = (lb & 7) * 128;
  const int srow = tid >> 3, sslot = tid & 7;
  f32x4 acc[4][4] = {};
  bf16x8 av[4], bv[4];
#pragma unroll
  for (int p = 0; p < 4; ++p) {
    av[p] = *(const bf16x8*)(A  + (size_t)(m0 + srow + p * 32) * DM_ + sslot * 8);
    bv[p] = *(const bf16x8*)(Bt + (size_t)(n0 + srow + p * 32) * DM_ + sslot * 8);
  }
  for (int k0 = 0; k0 < DM_; k0 += 64) {
    __syncthreads();
#pragma unroll
    for (int p = 0; p < 4; ++p) {
      const int r = srow + p * 32;
      *(bf16x8*)&sA[r][(sslot ^ (r & 7)) * 8] = av[p];
      *(bf16x8*)&sB[r][(sslot ^ (r & 7)) * 8] = bv[p];
    }
    if (k0 + 64 < DM_) {
#pragma unroll
      for (int p = 0; p < 4; ++p) {
        av[p] = *(const bf16x8*)(A  + (size_t)(m0 + srow + p * 32) * DM_ + k0 + 64 + sslot * 8);
        bv[p] = *(const bf16x8*)(Bt + (size_t)(n0 + srow + p * 32) * DM_ + k0 + 64 + sslot * 8);
      }
    }
    __syncthreads();
#pragma unroll
    for (int ks = 0; ks < 2; ++ks) {
      bf16x8 af[4], bf[4];
#pragma unroll
      for (int i = 0; i < 4; ++i) {
        const int r = wr * 64 + i * 16 + fr;
        af[i] = *(const bf16x8*)&sA[r][((ks * 4 + fg) ^ (r & 7)) * 8];
      }
#pragma unroll
      for (int j = 0; j < 4; ++j) {
        const int r = wc * 64 + j * 16 + fr;
        bf[j] = *(const bf16x8*)&sB[r][((ks * 4 + fg) ^ (r & 7)) * 8];
      }
#pragma unroll
      for (int i = 0; i < 4; ++i)
#pragma unroll
        for (int j = 0; j < 4; ++j)
          acc[i][j] = MFMA16(af[i], bf[j], acc[i][j]);
    }
  }
  const int m_blk = m0 + wr * 64, n_blk = n0 + wc * 64;
#pragma unroll
  for (int j = 0; j < 4; ++j) {
    const int n = n_blk + j * 16 + fr;
    const float bi = bias[n];
#pragma unroll
    for (int i = 0; i < 4; ++i)
#pragma unroll
      for (int r = 0; r < 4; ++r) {
        const int m = m_blk + i * 16 + fg * 4 + r;
        outp[(size_t)m * DM_ + n] = acc[i][j][r] + bi;
      }
  }
}

// ---------------- kvstate (MFMA, SC=128, 4 superchunks/block) --------------
__global__ __launch_bounds__(256) void kvstate_k(
    const u16* __restrict__ k, const u16* __restrict__ v,
    const u16* __restrict__ omb, const float* __restrict__ nhk,
    u16* __restrict__ stateb, float* __restrict__ ksum) {
  __shared__ u16 sPhi[256][72];
  __shared__ u16 sVt[64][72];
  const int tid = threadIdx.x, lane = tid & 63, w = tid >> 6;
  const int fr = lane & 15, fg = lane >> 4;
  const int bh = blockIdx.y;

  bf16x8 ones;
#pragma unroll
  for (int e = 0; e < 8; ++e) ones[e] = (short)0x3F80;

#pragma unroll 1
  for (int isc = 0; isc < 4; ++isc) {
    const int sc = blockIdx.x * 4 + isc;
    const size_t base_l = (size_t)bh * L_ + (size_t)sc * 128;

    f32x4 kvacc[4][4] = {};
    f32x4 ksacc[4] = {};

    for (int sub = 0; sub < 2; ++sub) {
      const size_t tl = base_l + sub * 64;
      const u16* kg = k + tl * 64;
      __syncthreads();   // fences prior sPhi/sVt readers (incl. prev isc)
      {
        const u16* vp = v + (tl + lane) * 64 + w * 16;
        bf16x8 v0 = *(const bf16x8*)(vp);
        bf16x8 v1 = *(const bf16x8*)(vp + 8);
#pragma unroll
        for (int e = 0; e < 8; ++e) sVt[w * 16 + e][lane] = (u16)v0[e];
#pragma unroll
        for (int e = 0; e < 8; ++e) sVt[w * 16 + 8 + e][lane] = (u16)v1[e];
      }
      float nhr[4];
#pragma unroll
      for (int tt = 0; tt < 4; ++tt) nhr[tt] = nhk[tl + tt * 16 + fr];
#pragma unroll
      for (int mi = 0; mi < 4; ++mi) {
        const int m0 = (w << 6) + mi * 16;
        const bf16x8 a0 = *(const bf16x8*)(omb + (m0 + fr) * 64 + fg * 8);
        const bf16x8 a1 = *(const bf16x8*)(omb + (m0 + fr) * 64 + 32 + fg * 8);
#pragma unroll
        for (int tt = 0; tt < 4; ++tt) {
          const bf16x8 b0 = *(const bf16x8*)(kg + (tt * 16 + fr) * 64 + fg * 8);
          const bf16x8 b1 = *(const bf16x8*)(kg + (tt * 16 + fr) * 64 + 32 + fg * 8);
          f32x4 acc = {0.f, 0.f, 0.f, 0.f};
          acc = MFMA16(a0, b0, acc);
          acc = MFMA16(a1, b1, acc);
          const float nhv = nhr[tt];
#pragma unroll
          for (int r = 0; r < 4; ++r)
            sPhi[m0 + fg * 4 + r][tt * 16 + fr] = f2bf(__expf(acc[r] - nhv));
        }
      }
      __syncthreads();
#pragma unroll
      for (int mi = 0; mi < 4; ++mi) {
        const int m0 = (w << 6) + mi * 16;
        const bf16x8 pb0 = *(const bf16x8*)&sPhi[m0 + fr][fg * 8];
        const bf16x8 pb1 = *(const bf16x8*)&sPhi[m0 + fr][32 + fg * 8];
        ksacc[mi] = MFMA16(pb0, ones, ksacc[mi]);
        ksacc[mi] = MFMA16(pb1, ones, ksacc[mi]);
#pragma unroll
        for (int dj = 0; dj < 4; ++dj) {
          const bf16x8 va0 = *(const bf16x8*)&sVt[dj * 16 + fr][fg * 8];
          const bf16x8 va1 = *(const bf16x8*)&sVt[dj * 16 + fr][32 + fg * 8];
          kvacc[mi][dj] = MFMA16(va0, pb0, kvacc[mi][dj]);
          kvacc[mi][dj] = MFMA16(va1, pb1, kvacc[mi][dj]);
        }
      }
    }
    // state bf16 [d][m]; ksum f32
    u16* stb = stateb + (size_t)(bh * NSC + sc) * (M_ * D_);
    float* ksp = ksum + (size_t)(bh * NSC + sc) * M_;
#pragma unroll
    for (int mi = 0; mi < 4; ++mi) {
      const int m = (w << 6) + mi * 16 + fr;
#pragma unroll
      for (int dj = 0; dj < 4; ++dj)
#pragma unroll
        for (int r = 0; r < 4; ++r)
          stb[(size_t)(dj * 16 + fg * 4 + r) * M_ + m] = f2bf(kvacc[mi][dj][r]);
      if (fr == 0) {
#pragma unroll
        for (int r = 0; r < 4; ++r)
          ksp[(w << 6) + mi * 16 + fg * 4 + r] = ksacc[mi][r];
      }
    }
  }
}

// ---------------- exclusive prefix over superchunks (bf16 state) -----------
__global__ __launch_bounds__(256) void scan_k(u16* __restrict__ stateb,
                                              float* __restrict__ ksum) {
  const int bh = blockIdx.y;
  u16* sb = stateb + (size_t)bh * NSC * (M_ * D_);
  const int base = blockIdx.x * 2048 + threadIdx.x * 8;
  float run[8] = {};
  for (int cc = 0; cc < NSC; ++cc) {
    u16* st = sb + (size_t)cc * (M_ * D_) + base;
    ushort4 t0 = *(ushort4*)st;
    ushort4 t1 = *(ushort4*)(st + 4);
    ushort4 w0, w1;
    w0.x = f2bf(run[0]); w0.y = f2bf(run[1]); w0.z = f2bf(run[2]); w0.w = f2bf(run[3]);
    w1.x = f2bf(run[4]); w1.y = f2bf(run[5]); w1.z = f2bf(run[6]); w1.w = f2bf(run[7]);
    *(ushort4*)st = w0;
    *(ushort4*)(st + 4) = w1;
    run[0] += bf2f(t0.x); run[1] += bf2f(t0.y); run[2] += bf2f(t0.z); run[3] += bf2f(t0.w);
    run[4] += bf2f(t1.x); run[5] += bf2f(t1.y); run[6] += bf2f(t1.z); run[7] += bf2f(t1.w);
  }
  if (blockIdx.x == 0) {           // ksum f32 in-place exclusive prefix
    float rk = 0.f;
    for (int cc = 0; cc < NSC; ++cc) {
      float* p = ksum + (size_t)(bh * NSC + cc) * M_ + threadIdx.x;
      const float t = *p;
      *p = rk;
      rk += t;
    }
  }
}

// ---------------- outchunk helpers -----------------------------------------
// phi quadrant from PRELOADED x-frags: writes ONLY rows of band wb
static __device__ __forceinline__ void phi_quad_r(
    bf16x8 a0, bf16x8 a1, const u16* __restrict__ ombq,
    u16* __restrict__ dst, int dstride, const float* nhv,
    int wb, int lane) {
  const int fr = lane & 15, fg = lane >> 4;
  const int tband = wb * 16;
#pragma unroll
  for (int j = 0; j < 4; ++j) {
    const bf16x8 b0 = *(const bf16x8*)(ombq + (j * 16 + fr) * 64 + fg * 8);
    const bf16x8 b1 = *(const bf16x8*)(ombq + (j * 16 + fr) * 64 + 32 + fg * 8);
    f32x4 acc = {0.f, 0.f, 0.f, 0.f};
    acc = MFMA16(a0, b0, acc);
    acc = MFMA16(a1, b1, acc);
#pragma unroll
    for (int r = 0; r < 4; ++r) {
      const int t = tband + fg * 4 + r;
      dst[t * dstride + j * 16 + fr] = f2bf(__expf(acc[r] - nhv[r]));
    }
  }
}

// ---------------- outchunk: 8 superchunks/block (R22 structure) ------------
__global__ __launch_bounds__(512, 2) void outchunk_k(
    const u16* __restrict__ q, const u16* __restrict__ kk,
    const u16* __restrict__ v, const u16* __restrict__ omb,
    const u16* __restrict__ stateb, const float* __restrict__ ksum,
    const float* __restrict__ nhq, const float* __restrict__ nhk,
    u16* __restrict__ attn) {
  __shared__ u16 sKa[64][264];    // Kp chunk0 (h0-produced)
  __shared__ u16 sKb[64][264];    // Kp chunk1 (h1-produced)
  __shared__ u16 sS0[64][72];     // h0 q-scratch / h0 masked S
  __shared__ u16 sS1[64][72];     // h1 q-scratch / h1 masked S
  __shared__ u16 sB1[64][72];     // vT chunk0 (h0-staged)
  __shared__ u16 sB2[64][72];     // vT chunk1 (h1-staged)
  __shared__ float ksum_l[256];   // total 105,472 B -> 1 block/CU
  const int tid = threadIdx.x, lane = tid & 63, w = tid >> 6;
  const int h = w >> 2, wl = w & 3;
  const int fr = lane & 15, fg = lane >> 4;
  const int bh = blockIdx.x >> 2, scp = blockIdx.x & 3;

#pragma unroll 1
  for (int it = 0; it < 8; ++it) {
    const int sc = scp * 8 + it;
    const size_t base_l = (size_t)bh * L_ + (size_t)sc * 128;
    const size_t tokq = base_l + (size_t)h * 64;
    const u16* qg = q + tokq * 64;
    const u16* stgb = stateb + (size_t)(bh * NSC + sc) * (M_ * D_);  // [d][m]
    const float* ksg = ksum + (size_t)(bh * NSC + sc) * M_;

    if (tid < 256) ksum_l[tid] = ksg[tid];

    // early v loads: half h loads its own chunk's v
    bf16x8 ev0, ev1;
    {
      const u16* vp = v + (base_l + (size_t)h * 64 + lane) * 64 + wl * 16;
      ev0 = *(const bf16x8*)(vp);
      ev1 = *(const bf16x8*)(vp + 8);
    }

    // phi(k): half h fills its chunk's Kp entirely (own rows, no syncs);
    // x-row loaded once (phi_quad_r).
    u16* kdst = (h == 0) ? &sKa[0][0] : &sKb[0][0];
    {
      const size_t ktokh = base_l + (size_t)h * 64;
      const u16* kgh = kk + ktokh * 64;
      float nhkh[4];
#pragma unroll
      for (int r = 0; r < 4; ++r) nhkh[r] = nhk[ktokh + wl * 16 + fg * 4 + r];
      const bf16x8 xk0 = *(const bf16x8*)(kgh + (wl * 16 + fr) * 64 + fg * 8);
      const bf16x8 xk1 = *(const bf16x8*)(kgh + (wl * 16 + fr) * 64 + 32 + fg * 8);
#pragma unroll
      for (int mq = 0; mq < 4; ++mq)
        phi_quad_r(xk0, xk1, omb + mq * 4096, kdst + mq * 64, 264, nhkh, wl, lane);
    }

    // phi(q) -> regs via own half's S buffer as scratch (wave-private rows);
    // cross term fused; x-row loaded once.
    float nhq4[4];
#pragma unroll
    for (int r = 0; r < 4; ++r) nhq4[r] = nhq[tokq + wl * 16 + fg * 4 + r];
    u16* myscr = (h == 0) ? &sS0[0][0] : &sS1[0][0];
    const bf16x8 xq0 = *(const bf16x8*)(qg + (wl * 16 + fr) * 64 + fg * 8);
    const bf16x8 xq1 = *(const bf16x8*)(qg + (wl * 16 + fr) * 64 + 32 + fg * 8);
    bf16x8 qa0[2], qa1[2], qa2[2], qa3[2];
    f32x4 oacc[4] = {};
#define QPHASE(MQ, QA)                                                          \
    {                                                                           \
      bf16x8 b0r[4], b1r[4];                                                    \
      _Pragma("unroll")                                                         \
      for (int j = 0; j < 4; ++j) {                                             \
        b0r[j] = *(const bf16x8*)(stgb + (size_t)(j * 16 + fr) * M_ + MQ * 64 + fg * 8);      \
        b1r[j] = *(const bf16x8*)(stgb + (size_t)(j * 16 + fr) * M_ + MQ * 64 + 32 + fg * 8); \
      }                                                                         \
      phi_quad_r(xq0, xq1, omb + MQ * 4096, myscr, 72, nhq4, wl, lane);         \
      QA[0] = *(const bf16x8*)(myscr + (wl * 16 + fr) * 72 + fg * 8);           \
      QA[1] = *(const bf16x8*)(myscr + (wl * 16 + fr) * 72 + 32 + fg * 8);      \
      __builtin_amdgcn_s_setprio(1);                                            \
      _Pragma("unroll")                                                         \
      for (int j = 0; j < 4; ++j) {                                             \
        oacc[j] = MFMA16(QA[0], b0r[j], oacc[j]);                               \
        oacc[j] = MFMA16(QA[1], b1r[j], oacc[j]);                               \
      }                                                                         \
      __builtin_amdgcn_s_setprio(0);                                            \
    }
    QPHASE(0, qa0)
    QPHASE(1, qa1)
    QPHASE(2, qa2)
    QPHASE(3, qa3)
#undef QPHASE
    __syncthreads();   // BAR K: ksum_l + full Kp (sKa/sKb) visible to all

    // den-ksum from register frags
    float denk = 0.f;
#pragma unroll
    for (int e = 0; e < 8; ++e) {
      denk += bf2f((u16)qa0[0][e]) * ksum_l[0   + fg * 8 + e]
            + bf2f((u16)qa0[1][e]) * ksum_l[32  + fg * 8 + e]
            + bf2f((u16)qa1[0][e]) * ksum_l[64  + fg * 8 + e]
            + bf2f((u16)qa1[1][e]) * ksum_l[96  + fg * 8 + e]
            + bf2f((u16)qa2[0][e]) * ksum_l[128 + fg * 8 + e]
            + bf2f((u16)qa2[1][e]) * ksum_l[160 + fg * 8 + e]
            + bf2f((u16)qa3[0][e]) * ksum_l[192 + fg * 8 + e]
            + bf2f((u16)qa3[1][e]) * ksum_l[224 + fg * 8 + e];
    }
    denk += __shfl_xor(denk, 16, 64);
    denk += __shfl_xor(denk, 32, 64);

    // ---- S chunk0 (all waves): 32 MFMA, B-frags from sKa
    float dS[4] = {0.f, 0.f, 0.f, 0.f};
    {
      f32x4 sacc[4] = {};
      __builtin_amdgcn_s_setprio(1);
#define SPH0(MQ, QA)                                                            \
      _Pragma("unroll")                                                         \
      for (int j = 0; j < 4; ++j) {                                             \
        const bf16x8 b0 = *(const bf16x8*)&sKa[j * 16 + fr][MQ * 64 + fg * 8];  \
        const bf16x8 b1 = *(const bf16x8*)&sKa[j * 16 + fr][MQ * 64 + 32 + fg * 8]; \
        sacc[j] = MFMA16(QA[0], b0, sacc[j]);                                   \
        sacc[j] = MFMA16(QA[1], b1, sacc[j]);                                   \
      }
      SPH0(0, qa0)
      SPH0(1, qa1)
      SPH0(2, qa2)
      SPH0(3, qa3)
#undef SPH0
      __builtin_amdgcn_s_setprio(0);
      u16 (*sSo)[72] = (h == 0) ? sS0 : sS1;
#pragma unroll
      for (int j = 0; j < 4; ++j)
#pragma unroll
        for (int r = 0; r < 4; ++r) {
          const int ss = j * 16 + fr, t = wl * 16 + fg * 4 + r;
          float val = sacc[j][r];
          if (h == 0 && ss > t) val = 0.f;
          const u16 vb = f2bf(val);
          sSo[t][ss] = vb;
          dS[r] += bf2f(vb);
        }
    }
    // vT staging: h0 -> sB1 (chunk0), h1 -> sB2 (chunk1)
    {
      u16 (*sBo)[72] = (h == 0) ? sB1 : sB2;
#pragma unroll
      for (int e = 0; e < 8; ++e) sBo[wl * 16 + e][lane] = (u16)ev0[e];
#pragma unroll
      for (int e = 0; e < 8; ++e) sBo[wl * 16 + 8 + e][lane] = (u16)ev1[e];
    }
    __syncthreads();   // BAR F0: sS0/sS1 + sB1/sB2 visible

    // ---- S@V chunk0 (all waves): A = own masked S (own band), B = sB1
    {
      const u16 (*sSo)[72] = (h == 0) ? sS0 : sS1;
      const bf16x8 a0 = *(const bf16x8*)&sSo[wl * 16 + fr][fg * 8];
      const bf16x8 a1 = *(const bf16x8*)&sSo[wl * 16 + fr][32 + fg * 8];
      __builtin_amdgcn_s_setprio(1);
#pragma unroll
      for (int j = 0; j < 4; ++j) {
        const bf16x8 b0 = *(const bf16x8*)&sB1[j * 16 + fr][fg * 8];
        const bf16x8 b1 = *(const bf16x8*)&sB1[j * 16 + fr][32 + fg * 8];
        oacc[j] = MFMA16(a0, b0, oacc[j]);
        oacc[j] = MFMA16(a1, b1, oacc[j]);
      }
      __builtin_amdgcn_s_setprio(0);
    }

    // ---- h1 only: S chunk1 (sKb) -> masked sS1 -> S@V chunk1 (sB2)
    if (h == 1) {
      f32x4 sacc[4] = {};
      __builtin_amdgcn_s_setprio(1);
#define SPH1(MQ, QA)                                                            \
      _Pragma("unroll")                                                         \
      for (int j = 0; j < 4; ++j) {                                             \
        const bf16x8 b0 = *(const bf16x8*)&sKb[j * 16 + fr][MQ * 64 + fg * 8];  \
        const bf16x8 b1 = *(const bf16x8*)&sKb[j * 16 + fr][MQ * 64 + 32 + fg * 8]; \
        sacc[j] = MFMA16(QA[0], b0, sacc[j]);                                   \
        sacc[j] = MFMA16(QA[1], b1, sacc[j]);                                   \
      }
      SPH1(0, qa0)
      SPH1(1, qa1)
      SPH1(2, qa2)
      SPH1(3, qa3)
#undef SPH1
      __builtin_amdgcn_s_setprio(0);
#pragma unroll
      for (int j = 0; j < 4; ++j)
#pragma unroll
        for (int r = 0; r < 4; ++r) {
          const int ss = j * 16 + fr, t = wl * 16 + fg * 4 + r;
          float val = sacc[j][r];
          if (ss > t) val = 0.f;         // diag (s == h == 1)
          const u16 vb = f2bf(val);
          sS1[t][ss] = vb;
          dS[r] += bf2f(vb);
        }
      {
        const bf16x8 a0 = *(const bf16x8*)&sS1[wl * 16 + fr][fg * 8];
        const bf16x8 a1 = *(const bf16x8*)&sS1[wl * 16 + fr][32 + fg * 8];
        __builtin_amdgcn_s_setprio(1);
#pragma unroll
        for (int j = 0; j < 4; ++j) {
          const bf16x8 b0 = *(const bf16x8*)&sB2[j * 16 + fr][fg * 8];
          const bf16x8 b1 = *(const bf16x8*)&sB2[j * 16 + fr][32 + fg * 8];
          oacc[j] = MFMA16(a0, b0, oacc[j]);
          oacc[j] = MFMA16(a1, b1, oacc[j]);
        }
        __builtin_amdgcn_s_setprio(0);
      }
    }

    // den: reduce dS over fr lanes; combine with denk via shfl
#pragma unroll
    for (int m2 = 1; m2 <= 8; m2 <<= 1) {
#pragma unroll
      for (int r = 0; r < 4; ++r) dS[r] += __shfl_xor(dS[r], m2, 64);
    }
    const int b = bh >> 4, hh = bh & 15;
#pragma unroll
    for (int r = 0; r < 4; ++r) {
      const float dk = __shfl(denk, fg * 4 + r, 64);   // token wl*16+fg*4+r
      const float rinv = 1.0f / (dk + dS[r] + 1e-6f);
      const int t = wl * 16 + fg * 4 + r;
      const int l = sc * 128 + h * 64 + t;
#pragma unroll
      for (int j = 0; j < 4; ++j) {
        const int d = j * 16 + fr;
        attn[((size_t)b * L_ + l) * DM_ + hh * 64 + d] = f2bf(oacc[j][r] * rinv);
      }
    }
    __syncthreads();   // BAR E: full fence before next superchunk's reuse
  }
}

extern "C" void kernel_launch(void* const* d_in, const int* in_sizes, int n_in,
                              void* d_out, int out_size, void* d_ws, size_t ws_size,
                              hipStream_t stream) {
  const float* x     = (const float*)d_in[0];
  const float* Wq    = (const float*)d_in[1];
  const float* bq    = (const float*)d_in[2];
  const float* Wk    = (const float*)d_in[3];
  const float* bk    = (const float*)d_in[4];
  const float* Wv    = (const float*)d_in[5];
  const float* bv    = (const float*)d_in[6];
  const float* Wo    = (const float*)d_in[7];
  const float* bo    = (const float*)d_in[8];
  const float* omega = (const float*)d_in[9];
  float* out = (float*)d_out;

  char* ws = (char*)d_ws;
  u16*   v      = (u16*)(ws);                           // 32 MB
  u16*   qb     = (u16*)(ws + 33554432ull);             // 32 MB
  u16*   kb     = (u16*)(ws + 67108864ull);             // 32 MB
  u16*   xb     = (u16*)(ws + 100663296ull);            // 32 MB (alias attn)
  u16*   attn   = xb;
  u16*   stateb = (u16*)(ws + 134217728ull);            // 64 MB
  float* ksum   = (float*)(ws + 201326592ull);          // 2 MB
  u16*   Wt     = (u16*)(ws + 203423744ull);            // 8 MB
  u16*   omb    = (u16*)(ws + 211812352ull);            // 32 KB
  float* nhq    = (float*)(ws + 211845120ull);          // 1 MB
  float* nhk    = (float*)(ws + 212893696ull);          // 1 MB -> 204 MB

  prep_k<<<3136, 256, 0, stream>>>(x, xb, Wq, Wk, Wv, Wo, Wt, omega, omb);
  mm3_k<<<1024, 256, 0, stream>>>(xb, Wt, bq, bk, bv, qb, kb, v, nhq, nhk);
  kvstate_k<<<dim3(NSC / 4, BH_), 256, 0, stream>>>(kb, v, omb, nhk, stateb, ksum);
  scan_k<<<dim3(8, BH_), 256, 0, stream>>>(stateb, ksum);
  outchunk_k<<<BH_ * (NSC / 8), 512, 0, stream>>>(qb, kb, v, omb, stateb, ksum,
                                                  nhq, nhk, attn);
  mmo_k<<<1024, 256, 0, stream>>>(attn, Wt + 3145728ull, bo, out);
}

// Round 26
// 437.896 us; speedup vs baseline: 1.1252x; 1.1252x over previous
//
#include <hip/hip_runtime.h>
#include <hip/hip_bf16.h>

// FAVOR+ attention, MI355X. Round 26: revert mm3 y-fold (R25 regression:
// killed inter-block overlap; occupancy 11%). mm3 back to grid (1024,3).
// Keep prep_k grid-stride convx. All else byte-identical to validated R24.
//
// Workspace (bytes), total 213,942,272 (~204 MB): layout as R17-R24.

#define B_ 4
#define H_ 16
#define L_ 4096
#define D_ 64
#define M_ 256
#define DM_ 1024
#define BH_ 64
#define NSC 32            // superchunks per bh (SC = 128 tokens)

typedef unsigned int u32;
typedef unsigned short u16;
typedef __attribute__((ext_vector_type(8))) short bf16x8;
typedef __attribute__((ext_vector_type(4))) float f32x4;

static __device__ __forceinline__ float bf2f(u16 u) {
  return __uint_as_float(((u32)u) << 16);
}
static __device__ __forceinline__ u16 f2bf(float f) {
  u32 x = __float_as_uint(f);
  return (u16)((x + 0x7fffu + ((x >> 16) & 1u)) >> 16);   // RNE
}
#define MFMA16(a, b, c) __builtin_amdgcn_mfma_f32_16x16x32_bf16((a), (b), (c), 0, 0, 0)
#define LN16 2.772588722239781f

// ---------------- merged prep: convx (grid-stride) | convw | convom --------
__global__ __launch_bounds__(256) void prep_k(
    const float* __restrict__ x, u16* __restrict__ xb,
    const float* __restrict__ W0, const float* __restrict__ W1,
    const float* __restrict__ W2, const float* __restrict__ W3,
    u16* __restrict__ Wt, const float* __restrict__ om,
    u16* __restrict__ omb) {
  __shared__ u16 tt[64][66];
  const int bid = blockIdx.x, tid = threadIdx.x;
  if (bid < 2048) {
    // convx: 4,194,304 float4s, 2048 blocks x 256 thr x 8 iters
#pragma unroll
    for (int s = 0; s < 8; ++s) {
      const int i = (bid * 256 + tid) + s * 524288;
      float4 f = ((const float4*)x)[i];
      ushort4 u;
      u.x = f2bf(f.x); u.y = f2bf(f.y); u.z = f2bf(f.z); u.w = f2bf(f.w);
      ((ushort4*)xb)[i] = u;
    }
  } else if (bid < 3072) {
    const int rem = bid - 2048;
    const int z = rem >> 8, r2 = rem & 255;
    const int k0 = (r2 >> 4) * 64, n0 = (r2 & 15) * 64;
    const float* W = (z == 0) ? W0 : (z == 1) ? W1 : (z == 2) ? W2 : W3;
    u16* o = Wt + (size_t)z * 1048576ull;
    const int r = tid >> 4, c4 = (tid & 15) << 2;
    for (int rr = r; rr < 64; rr += 16) {
      float4 w4 = *(const float4*)(W + (size_t)(k0 + rr) * DM_ + n0 + c4);
      tt[c4 + 0][rr] = f2bf(w4.x);
      tt[c4 + 1][rr] = f2bf(w4.y);
      tt[c4 + 2][rr] = f2bf(w4.z);
      tt[c4 + 3][rr] = f2bf(w4.w);
    }
    __syncthreads();
    for (int rr = r; rr < 64; rr += 16) {
      ushort4 u4;
      u4.x = tt[rr][c4 + 0];
      u4.y = tt[rr][c4 + 1];
      u4.z = tt[rr][c4 + 2];
      u4.w = tt[rr][c4 + 3];
      *(ushort4*)(o + (size_t)(n0 + rr) * DM_ + k0 + c4) = u4;
    }
  } else {
    const int i = (bid - 3072) * 256 + tid;
    omb[i] = f2bf(om[i] * 0.35355339059327373f);     // fold 64^-0.25
  }
}

// ---------------- merged projection GEMMs (q,k,v), head bf16 out -----------
// grid (1024, 3): y selects {Wq->qb(+nhq), Wk->kb(+nhk), Wv->v}
// nh' = 0.0625 * sum(bf2f(f2bf(v))^2) + ln16  (phi scale folded in)
__global__ __launch_bounds__(256) void mm3_k(
    const u16* __restrict__ A, const u16* __restrict__ Wt,
    const float* __restrict__ bq, const float* __restrict__ bk,
    const float* __restrict__ bv, u16* __restrict__ qb,
    u16* __restrict__ kb, u16* __restrict__ vb,
    float* __restrict__ nhq, float* __restrict__ nhk) {
  __shared__ u16 sA[128][64];   // 16 KB, XOR-swizzled 16B slots
  __shared__ u16 sB[128][64];   // 16 KB
  const int y = blockIdx.y;
  const u16* Bt = Wt + (size_t)y * 1048576ull;
  const float* bias = (y == 0) ? bq : (y == 1) ? bk : bv;
  u16* outp = (y == 0) ? qb : (y == 1) ? kb : vb;
  float* nhout = (y == 0) ? nhq : (y == 1) ? nhk : nullptr;
  const int tid = threadIdx.x, lane = tid & 63, w = tid >> 6;
  const int fr = lane & 15, fg = lane >> 4;
  const int wr = w >> 1, wc = w & 1;
  const int lb = ((blockIdx.x & 7) << 7) | (blockIdx.x >> 3);
  const int m0 = (lb >> 3) * 128, n0 = (lb & 7) * 128;
  const int srow = tid >> 3, sslot = tid & 7;   // +p*32 rows per pass
  f32x4 acc[4][4] = {};
  bf16x8 av[4], bv4[4];
#pragma unroll
  for (int p = 0; p < 4; ++p) {
    av[p]  = *(const bf16x8*)(A  + (size_t)(m0 + srow + p * 32) * DM_ + sslot * 8);
    bv4[p] = *(const bf16x8*)(Bt + (size_t)(n0 + srow + p * 32) * DM_ + sslot * 8);
  }
  for (int k0 = 0; k0 < DM_; k0 += 64) {
    __syncthreads();
#pragma unroll
    for (int p = 0; p < 4; ++p) {
      const int r = srow + p * 32;
      *(bf16x8*)&sA[r][(sslot ^ (r & 7)) * 8] = av[p];
      *(bf16x8*)&sB[r][(sslot ^ (r & 7)) * 8] = bv4[p];
    }
    if (k0 + 64 < DM_) {
#pragma unroll
      for (int p = 0; p < 4; ++p) {
        av[p]  = *(const bf16x8*)(A  + (size_t)(m0 + srow + p * 32) * DM_ + k0 + 64 + sslot * 8);
        bv4[p] = *(const bf16x8*)(Bt + (size_t)(n0 + srow + p * 32) * DM_ + k0 + 64 + sslot * 8);
      }
    }
    __syncthreads();
#pragma unroll
    for (int ks = 0; ks < 2; ++ks) {
      bf16x8 af[4], bf[4];
#pragma unroll
      for (int i = 0; i < 4; ++i) {
        const int r = wr * 64 + i * 16 + fr;
        af[i] = *(const bf16x8*)&sA[r][((ks * 4 + fg) ^ (r & 7)) * 8];
      }
#pragma unroll
      for (int j = 0; j < 4; ++j) {
        const int r = wc * 64 + j * 16 + fr;
        bf[j] = *(const bf16x8*)&sB[r][((ks * 4 + fg) ^ (r & 7)) * 8];
      }
#pragma unroll
      for (int i = 0; i < 4; ++i)
#pragma unroll
        for (int j = 0; j < 4; ++j)
          acc[i][j] = MFMA16(af[i], bf[j], acc[i][j]);
    }
  }
  const int m_blk = m0 + wr * 64, n_blk = n0 + wc * 64;
  float nhacc[4][4] = {};
#pragma unroll
  for (int j = 0; j < 4; ++j) {
    const int n = n_blk + j * 16 + fr;
    const float bi = bias[n];
    const int h = n >> 6, d = n & 63;
#pragma unroll
    for (int i = 0; i < 4; ++i) {
#pragma unroll
      for (int r = 0; r < 4; ++r) {
        const int m = m_blk + i * 16 + fg * 4 + r;
        const float val = acc[i][j][r] + bi;
        const int b = m >> 12, l = m & 4095;
        const u16 sv = f2bf(val);
        outp[((size_t)(b * H_ + h) * L_ + l) * D_ + d] = sv;
        const float rv = bf2f(sv);
        nhacc[i][r] += rv * rv;
      }
    }
  }
  if (nhout) {
    const int hh2 = n_blk >> 6;
#pragma unroll
    for (int i = 0; i < 4; ++i)
#pragma unroll
      for (int r = 0; r < 4; ++r) {
        float s = nhacc[i][r];
        s += __shfl_xor(s, 1, 64);
        s += __shfl_xor(s, 2, 64);
        s += __shfl_xor(s, 4, 64);
        s += __shfl_xor(s, 8, 64);
        if (fr == 0) {
          const int m = m_blk + i * 16 + fg * 4 + r;
          const int b = m >> 12, l = m & 4095;
          nhout[(size_t)(b * H_ + hh2) * L_ + l] = 0.0625f * s + LN16;
        }
      }
  }
}

// ---------------- final GEMM (attn bf16 -> f32 out), validated -------------
__global__ __launch_bounds__(256) void mmo_k(
    const u16* __restrict__ A, const u16* __restrict__ Bt,
    const float* __restrict__ bias, float* __restrict__ outp) {
  __shared__ u16 sA[128][64];
  __shared__ u16 sB[128][64];
  const int tid = threadIdx.x, lane = tid & 63, w = tid >> 6;
  const int fr = lane & 15, fg = lane >> 4;
  const int wr = w >> 1, wc = w & 1;
  const int lb = ((blockIdx.x & 7) << 7) | (blockIdx.x >> 3);
  const int m0 = (lb >> 3) * 128, n0 = (lb & 7) * 128;
  const int srow = tid >> 3, sslot = tid & 7;
  f32x4 acc[4][4] = {};
  bf16x8 av[4], bv[4];
#pragma unroll
  for (int p = 0; p < 4; ++p) {
    av[p] = *(const bf16x8*)(A  + (size_t)(m0 + srow + p * 32) * DM_ + sslot * 8);
    bv[p] = *(const bf16x8*)(Bt + (size_t)(n0 + srow + p * 32) * DM_ + sslot * 8);
  }
  for (int k0 = 0; k0 < DM_; k0 += 64) {
    __syncthreads();
#pragma unroll
    for (int p = 0; p < 4; ++p) {
      const int r = srow + p * 32;
      *(bf16x8*)&sA[r][(sslot ^ (r & 7)) * 8] = av[p];
      *(bf16x8*)&sB[r][(sslot ^ (r & 7)) * 8] = bv[p];
    }
    if (k0 + 64 < DM_) {
#pragma unroll
      for (int p = 0; p < 4; ++p) {
        av[p] = *(const bf16x8*)(A  + (size_t)(m0 + srow + p * 32) * DM_ + k0 + 64 + sslot * 8);
        bv[p] = *(const bf16x8*)(Bt + (size_t)(n0 + srow + p * 32) * DM_ + k0 + 64 + sslot * 8);
      }
    }
    __syncthreads();
#pragma unroll
    for (int ks = 0; ks < 2; ++ks) {
      bf16x8 af[4], bf[4];
#pragma unroll
      for (int i = 0; i < 4; ++i) {
        const int r = wr * 64 + i * 16 + fr;
        af[i] = *(const bf16x8*)&sA[r][((ks * 4 + fg) ^ (r & 7)) * 8];
      }
#pragma unroll
      for (int j = 0; j < 4; ++j) {
        const int r = wc * 64 + j * 16 + fr;
        bf[j] = *(const bf16x8*)&sB[r][((ks * 4 + fg) ^ (r & 7)) * 8];
      }
#pragma unroll
      for (int i = 0; i < 4; ++i)
#pragma unroll
        for (int j = 0; j < 4; ++j)
          acc[i][j] = MFMA16(af[i], bf[j], acc[i][j]);
    }
  }
  const int m_blk = m0 + wr * 64, n_blk = n0 + wc * 64;
#pragma unroll
  for (int j = 0; j < 4; ++j) {
    const int n = n_blk + j * 16 + fr;
    const float bi = bias[n];
#pragma unroll
    for (int i = 0; i < 4; ++i)
#pragma unroll
      for (int r = 0; r < 4; ++r) {
        const int m = m_blk + i * 16 + fg * 4 + r;
        outp[(size_t)m * DM_ + n] = acc[i][j][r] + bi;
      }
  }
}

// ---------------- kvstate (MFMA, SC=128, 4 superchunks/block) --------------
__global__ __launch_bounds__(256) void kvstate_k(
    const u16* __restrict__ k, const u16* __restrict__ v,
    const u16* __restrict__ omb, const float* __restrict__ nhk,
    u16* __restrict__ stateb, float* __restrict__ ksum) {
  __shared__ u16 sPhi[256][72];
  __shared__ u16 sVt[64][72];
  const int tid = threadIdx.x, lane = tid & 63, w = tid >> 6;
  const int fr = lane & 15, fg = lane >> 4;
  const int bh = blockIdx.y;

  bf16x8 ones;
#pragma unroll
  for (int e = 0; e < 8; ++e) ones[e] = (short)0x3F80;

#pragma unroll 1
  for (int isc = 0; isc < 4; ++isc) {
    const int sc = blockIdx.x * 4 + isc;
    const size_t base_l = (size_t)bh * L_ + (size_t)sc * 128;

    f32x4 kvacc[4][4] = {};
    f32x4 ksacc[4] = {};

    for (int sub = 0; sub < 2; ++sub) {
      const size_t tl = base_l + sub * 64;
      const u16* kg = k + tl * 64;
      __syncthreads();   // fences prior sPhi/sVt readers (incl. prev isc)
      {
        const u16* vp = v + (tl + lane) * 64 + w * 16;
        bf16x8 v0 = *(const bf16x8*)(vp);
        bf16x8 v1 = *(const bf16x8*)(vp + 8);
#pragma unroll
        for (int e = 0; e < 8; ++e) sVt[w * 16 + e][lane] = (u16)v0[e];
#pragma unroll
        for (int e = 0; e < 8; ++e) sVt[w * 16 + 8 + e][lane] = (u16)v1[e];
      }
      float nhr[4];
#pragma unroll
      for (int tt = 0; tt < 4; ++tt) nhr[tt] = nhk[tl + tt * 16 + fr];
#pragma unroll
      for (int mi = 0; mi < 4; ++mi) {
        const int m0 = (w << 6) + mi * 16;
        const bf16x8 a0 = *(const bf16x8*)(omb + (m0 + fr) * 64 + fg * 8);
        const bf16x8 a1 = *(const bf16x8*)(omb + (m0 + fr) * 64 + 32 + fg * 8);
#pragma unroll
        for (int tt = 0; tt < 4; ++tt) {
          const bf16x8 b0 = *(const bf16x8*)(kg + (tt * 16 + fr) * 64 + fg * 8);
          const bf16x8 b1 = *(const bf16x8*)(kg + (tt * 16 + fr) * 64 + 32 + fg * 8);
          f32x4 acc = {0.f, 0.f, 0.f, 0.f};
          acc = MFMA16(a0, b0, acc);
          acc = MFMA16(a1, b1, acc);
          const float nhv = nhr[tt];
#pragma unroll
          for (int r = 0; r < 4; ++r)
            sPhi[m0 + fg * 4 + r][tt * 16 + fr] = f2bf(__expf(acc[r] - nhv));
        }
      }
      __syncthreads();
#pragma unroll
      for (int mi = 0; mi < 4; ++mi) {
        const int m0 = (w << 6) + mi * 16;
        const bf16x8 pb0 = *(const bf16x8*)&sPhi[m0 + fr][fg * 8];
        const bf16x8 pb1 = *(const bf16x8*)&sPhi[m0 + fr][32 + fg * 8];
        ksacc[mi] = MFMA16(pb0, ones, ksacc[mi]);
        ksacc[mi] = MFMA16(pb1, ones, ksacc[mi]);
#pragma unroll
        for (int dj = 0; dj < 4; ++dj) {
          const bf16x8 va0 = *(const bf16x8*)&sVt[dj * 16 + fr][fg * 8];
          const bf16x8 va1 = *(const bf16x8*)&sVt[dj * 16 + fr][32 + fg * 8];
          kvacc[mi][dj] = MFMA16(va0, pb0, kvacc[mi][dj]);
          kvacc[mi][dj] = MFMA16(va1, pb1, kvacc[mi][dj]);
        }
      }
    }
    // state bf16 [d][m]; ksum f32
    u16* stb = stateb + (size_t)(bh * NSC + sc) * (M_ * D_);
    float* ksp = ksum + (size_t)(bh * NSC + sc) * M_;
#pragma unroll
    for (int mi = 0; mi < 4; ++mi) {
      const int m = (w << 6) + mi * 16 + fr;
#pragma unroll
      for (int dj = 0; dj < 4; ++dj)
#pragma unroll
        for (int r = 0; r < 4; ++r)
          stb[(size_t)(dj * 16 + fg * 4 + r) * M_ + m] = f2bf(kvacc[mi][dj][r]);
      if (fr == 0) {
#pragma unroll
        for (int r = 0; r < 4; ++r)
          ksp[(w << 6) + mi * 16 + fg * 4 + r] = ksacc[mi][r];
      }
    }
  }
}

// ---------------- exclusive prefix over superchunks (bf16 state) -----------
__global__ __launch_bounds__(256) void scan_k(u16* __restrict__ stateb,
                                              float* __restrict__ ksum) {
  const int bh = blockIdx.y;
  u16* sb = stateb + (size_t)bh * NSC * (M_ * D_);
  const int base = blockIdx.x * 2048 + threadIdx.x * 8;
  float run[8] = {};
  for (int cc = 0; cc < NSC; ++cc) {
    u16* st = sb + (size_t)cc * (M_ * D_) + base;
    ushort4 t0 = *(ushort4*)st;
    ushort4 t1 = *(ushort4*)(st + 4);
    ushort4 w0, w1;
    w0.x = f2bf(run[0]); w0.y = f2bf(run[1]); w0.z = f2bf(run[2]); w0.w = f2bf(run[3]);
    w1.x = f2bf(run[4]); w1.y = f2bf(run[5]); w1.z = f2bf(run[6]); w1.w = f2bf(run[7]);
    *(ushort4*)st = w0;
    *(ushort4*)(st + 4) = w1;
    run[0] += bf2f(t0.x); run[1] += bf2f(t0.y); run[2] += bf2f(t0.z); run[3] += bf2f(t0.w);
    run[4] += bf2f(t1.x); run[5] += bf2f(t1.y); run[6] += bf2f(t1.z); run[7] += bf2f(t1.w);
  }
  if (blockIdx.x == 0) {           // ksum f32 in-place exclusive prefix
    float rk = 0.f;
    for (int cc = 0; cc < NSC; ++cc) {
      float* p = ksum + (size_t)(bh * NSC + cc) * M_ + threadIdx.x;
      const float t = *p;
      *p = rk;
      rk += t;
    }
  }
}

// ---------------- outchunk helpers -----------------------------------------
// phi quadrant from PRELOADED x-frags: writes ONLY rows of band wb
static __device__ __forceinline__ void phi_quad_r(
    bf16x8 a0, bf16x8 a1, const u16* __restrict__ ombq,
    u16* __restrict__ dst, int dstride, const float* nhv,
    int wb, int lane) {
  const int fr = lane & 15, fg = lane >> 4;
  const int tband = wb * 16;
#pragma unroll
  for (int j = 0; j < 4; ++j) {
    const bf16x8 b0 = *(const bf16x8*)(ombq + (j * 16 + fr) * 64 + fg * 8);
    const bf16x8 b1 = *(const bf16x8*)(ombq + (j * 16 + fr) * 64 + 32 + fg * 8);
    f32x4 acc = {0.f, 0.f, 0.f, 0.f};
    acc = MFMA16(a0, b0, acc);
    acc = MFMA16(a1, b1, acc);
#pragma unroll
    for (int r = 0; r < 4; ++r) {
      const int t = tband + fg * 4 + r;
      dst[t * dstride + j * 16 + fr] = f2bf(__expf(acc[r] - nhv[r]));
    }
  }
}

// ---------------- outchunk: 8 superchunks/block (R22/R24 structure) --------
__global__ __launch_bounds__(512, 2) void outchunk_k(
    const u16* __restrict__ q, const u16* __restrict__ kk,
    const u16* __restrict__ v, const u16* __restrict__ omb,
    const u16* __restrict__ stateb, const float* __restrict__ ksum,
    const float* __restrict__ nhq, const float* __restrict__ nhk,
    u16* __restrict__ attn) {
  __shared__ u16 sKa[64][264];    // Kp chunk0 (h0-produced)
  __shared__ u16 sKb[64][264];    // Kp chunk1 (h1-produced)
  __shared__ u16 sS0[64][72];     // h0 q-scratch / h0 masked S
  __shared__ u16 sS1[64][72];     // h1 q-scratch / h1 masked S
  __shared__ u16 sB1[64][72];     // vT chunk0 (h0-staged)
  __shared__ u16 sB2[64][72];     // vT chunk1 (h1-staged)
  __shared__ float ksum_l[256];   // total 105,472 B -> 1 block/CU
  const int tid = threadIdx.x, lane = tid & 63, w = tid >> 6;
  const int h = w >> 2, wl = w & 3;
  const int fr = lane & 15, fg = lane >> 4;
  const int bh = blockIdx.x >> 2, scp = blockIdx.x & 3;

#pragma unroll 1
  for (int it = 0; it < 8; ++it) {
    const int sc = scp * 8 + it;
    const size_t base_l = (size_t)bh * L_ + (size_t)sc * 128;
    const size_t tokq = base_l + (size_t)h * 64;
    const u16* qg = q + tokq * 64;
    const u16* stgb = stateb + (size_t)(bh * NSC + sc) * (M_ * D_);  // [d][m]
    const float* ksg = ksum + (size_t)(bh * NSC + sc) * M_;

    if (tid < 256) ksum_l[tid] = ksg[tid];

    // early v loads: half h loads its own chunk's v
    bf16x8 ev0, ev1;
    {
      const u16* vp = v + (base_l + (size_t)h * 64 + lane) * 64 + wl * 16;
      ev0 = *(const bf16x8*)(vp);
      ev1 = *(const bf16x8*)(vp + 8);
    }

    // phi(k): half h fills its chunk's Kp entirely (own rows, no syncs);
    // x-row loaded once (phi_quad_r).
    u16* kdst = (h == 0) ? &sKa[0][0] : &sKb[0][0];
    {
      const size_t ktokh = base_l + (size_t)h * 64;
      const u16* kgh = kk + ktokh * 64;
      float nhkh[4];
#pragma unroll
      for (int r = 0; r < 4; ++r) nhkh[r] = nhk[ktokh + wl * 16 + fg * 4 + r];
      const bf16x8 xk0 = *(const bf16x8*)(kgh + (wl * 16 + fr) * 64 + fg * 8);
      const bf16x8 xk1 = *(const bf16x8*)(kgh + (wl * 16 + fr) * 64 + 32 + fg * 8);
#pragma unroll
      for (int mq = 0; mq < 4; ++mq)
        phi_quad_r(xk0, xk1, omb + mq * 4096, kdst + mq * 64, 264, nhkh, wl, lane);
    }

    // phi(q) -> regs via own half's S buffer as scratch (wave-private rows);
    // cross term fused; x-row loaded once.
    float nhq4[4];
#pragma unroll
    for (int r = 0; r < 4; ++r) nhq4[r] = nhq[tokq + wl * 16 + fg * 4 + r];
    u16* myscr = (h == 0) ? &sS0[0][0] : &sS1[0][0];
    const bf16x8 xq0 = *(const bf16x8*)(qg + (wl * 16 + fr) * 64 + fg * 8);
    const bf16x8 xq1 = *(const bf16x8*)(qg + (wl * 16 + fr) * 64 + 32 + fg * 8);
    bf16x8 qa0[2], qa1[2], qa2[2], qa3[2];
    f32x4 oacc[4] = {};
#define QPHASE(MQ, QA)                                                          \
    {                                                                           \
      bf16x8 b0r[4], b1r[4];                                                    \
      _Pragma("unroll")                                                         \
      for (int j = 0; j < 4; ++j) {                                             \
        b0r[j] = *(const bf16x8*)(stgb + (size_t)(j * 16 + fr) * M_ + MQ * 64 + fg * 8);      \
        b1r[j] = *(const bf16x8*)(stgb + (size_t)(j * 16 + fr) * M_ + MQ * 64 + 32 + fg * 8); \
      }                                                                         \
      phi_quad_r(xq0, xq1, omb + MQ * 4096, myscr, 72, nhq4, wl, lane);         \
      QA[0] = *(const bf16x8*)(myscr + (wl * 16 + fr) * 72 + fg * 8);           \
      QA[1] = *(const bf16x8*)(myscr + (wl * 16 + fr) * 72 + 32 + fg * 8);      \
      __builtin_amdgcn_s_setprio(1);                                            \
      _Pragma("unroll")                                                         \
      for (int j = 0; j < 4; ++j) {                                             \
        oacc[j] = MFMA16(QA[0], b0r[j], oacc[j]);                               \
        oacc[j] = MFMA16(QA[1], b1r[j], oacc[j]);                               \
      }                                                                         \
      __builtin_amdgcn_s_setprio(0);                                            \
    }
    QPHASE(0, qa0)
    QPHASE(1, qa1)
    QPHASE(2, qa2)
    QPHASE(3, qa3)
#undef QPHASE
    __syncthreads();   // BAR K: ksum_l + full Kp (sKa/sKb) visible to all

    // den-ksum from register frags
    float denk = 0.f;
#pragma unroll
    for (int e = 0; e < 8; ++e) {
      denk += bf2f((u16)qa0[0][e]) * ksum_l[0   + fg * 8 + e]
            + bf2f((u16)qa0[1][e]) * ksum_l[32  + fg * 8 + e]
            + bf2f((u16)qa1[0][e]) * ksum_l[64  + fg * 8 + e]
            + bf2f((u16)qa1[1][e]) * ksum_l[96  + fg * 8 + e]
            + bf2f((u16)qa2[0][e]) * ksum_l[128 + fg * 8 + e]
            + bf2f((u16)qa2[1][e]) * ksum_l[160 + fg * 8 + e]
            + bf2f((u16)qa3[0][e]) * ksum_l[192 + fg * 8 + e]
            + bf2f((u16)qa3[1][e]) * ksum_l[224 + fg * 8 + e];
    }
    denk += __shfl_xor(denk, 16, 64);
    denk += __shfl_xor(denk, 32, 64);

    // ---- S chunk0 (all waves): 32 MFMA, B-frags from sKa
    float dS[4] = {0.f, 0.f, 0.f, 0.f};
    {
      f32x4 sacc[4] = {};
      __builtin_amdgcn_s_setprio(1);
#define SPH0(MQ, QA)                                                            \
      _Pragma("unroll")                                                         \
      for (int j = 0; j < 4; ++j) {                                             \
        const bf16x8 b0 = *(const bf16x8*)&sKa[j * 16 + fr][MQ * 64 + fg * 8];  \
        const bf16x8 b1 = *(const bf16x8*)&sKa[j * 16 + fr][MQ * 64 + 32 + fg * 8]; \
        sacc[j] = MFMA16(QA[0], b0, sacc[j]);                                   \
        sacc[j] = MFMA16(QA[1], b1, sacc[j]);                                   \
      }
      SPH0(0, qa0)
      SPH0(1, qa1)
      SPH0(2, qa2)
      SPH0(3, qa3)
#undef SPH0
      __builtin_amdgcn_s_setprio(0);
      u16 (*sSo)[72] = (h == 0) ? sS0 : sS1;
#pragma unroll
      for (int j = 0; j < 4; ++j)
#pragma unroll
        for (int r = 0; r < 4; ++r) {
          const int ss = j * 16 + fr, t = wl * 16 + fg * 4 + r;
          float val = sacc[j][r];
          if (h == 0 && ss > t) val = 0.f;
          const u16 vb = f2bf(val);
          sSo[t][ss] = vb;
          dS[r] += bf2f(vb);
        }
    }
    // vT staging: h0 -> sB1 (chunk0), h1 -> sB2 (chunk1)
    {
      u16 (*sBo)[72] = (h == 0) ? sB1 : sB2;
#pragma unroll
      for (int e = 0; e < 8; ++e) sBo[wl * 16 + e][lane] = (u16)ev0[e];
#pragma unroll
      for (int e = 0; e < 8; ++e) sBo[wl * 16 + 8 + e][lane] = (u16)ev1[e];
    }
    __syncthreads();   // BAR F0: sS0/sS1 + sB1/sB2 visible

    // ---- S@V chunk0 (all waves): A = own masked S (own band), B = sB1
    {
      const u16 (*sSo)[72] = (h == 0) ? sS0 : sS1;
      const bf16x8 a0 = *(const bf16x8*)&sSo[wl * 16 + fr][fg * 8];
      const bf16x8 a1 = *(const bf16x8*)&sSo[wl * 16 + fr][32 + fg * 8];
      __builtin_amdgcn_s_setprio(1);
#pragma unroll
      for (int j = 0; j < 4; ++j) {
        const bf16x8 b0 = *(const bf16x8*)&sB1[j * 16 + fr][fg * 8];
        const bf16x8 b1 = *(const bf16x8*)&sB1[j * 16 + fr][32 + fg * 8];
        oacc[j] = MFMA16(a0, b0, oacc[j]);
        oacc[j] = MFMA16(a1, b1, oacc[j]);
      }
      __builtin_amdgcn_s_setprio(0);
    }

    // ---- h1 only: S chunk1 (sKb) -> masked sS1 -> S@V chunk1 (sB2)
    if (h == 1) {
      f32x4 sacc[4] = {};
      __builtin_amdgcn_s_setprio(1);
#define SPH1(MQ, QA)                                                            \
      _Pragma("unroll")                                                         \
      for (int j = 0; j < 4; ++j) {                                             \
        const bf16x8 b0 = *(const bf16x8*)&sKb[j * 16 + fr][MQ * 64 + fg * 8];  \
        const bf16x8 b1 = *(const bf16x8*)&sKb[j * 16 + fr][MQ * 64 + 32 + fg * 8]; \
        sacc[j] = MFMA16(QA[0], b0, sacc[j]);                                   \
        sacc[j] = MFMA16(QA[1], b1, sacc[j]);                                   \
      }
      SPH1(0, qa0)
      SPH1(1, qa1)
      SPH1(2, qa2)
      SPH1(3, qa3)
#undef SPH1
      __builtin_amdgcn_s_setprio(0);
#pragma unroll
      for (int j = 0; j < 4; ++j)
#pragma unroll
        for (int r = 0; r < 4; ++r) {
          const int ss = j * 16 + fr, t = wl * 16 + fg * 4 + r;
          float val = sacc[j][r];
          if (ss > t) val = 0.f;         // diag (s == h == 1)
          const u16 vb = f2bf(val);
          sS1[t][ss] = vb;
          dS[r] += bf2f(vb);
        }
      {
        const bf16x8 a0 = *(const bf16x8*)&sS1[wl * 16 + fr][fg * 8];
        const bf16x8 a1 = *(const bf16x8*)&sS1[wl * 16 + fr][32 + fg * 8];
        __builtin_amdgcn_s_setprio(1);
#pragma unroll
        for (int j = 0; j < 4; ++j) {
          const bf16x8 b0 = *(const bf16x8*)&sB2[j * 16 + fr][fg * 8];
          const bf16x8 b1 = *(const bf16x8*)&sB2[j * 16 + fr][32 + fg * 8];
          oacc[j] = MFMA16(a0, b0, oacc[j]);
          oacc[j] = MFMA16(a1, b1, oacc[j]);
        }
        __builtin_amdgcn_s_setprio(0);
      }
    }

    // den: reduce dS over fr lanes; combine with denk via shfl
#pragma unroll
    for (int m2 = 1; m2 <= 8; m2 <<= 1) {
#pragma unroll
      for (int r = 0; r < 4; ++r) dS[r] += __shfl_xor(dS[r], m2, 64);
    }
    const int b = bh >> 4, hh = bh & 15;
#pragma unroll
    for (int r = 0; r < 4; ++r) {
      const float dk = __shfl(denk, fg * 4 + r, 64);   // token wl*16+fg*4+r
      const float rinv = 1.0f / (dk + dS[r] + 1e-6f);
      const int t = wl * 16 + fg * 4 + r;
      const int l = sc * 128 + h * 64 + t;
#pragma unroll
      for (int j = 0; j < 4; ++j) {
        const int d = j * 16 + fr;
        attn[((size_t)b * L_ + l) * DM_ + hh * 64 + d] = f2bf(oacc[j][r] * rinv);
      }
    }
    __syncthreads();   // BAR E: full fence before next superchunk's reuse
  }
}

extern "C" void kernel_launch(void* const* d_in, const int* in_sizes, int n_in,
                              void* d_out, int out_size, void* d_ws, size_t ws_size,
                              hipStream_t stream) {
  const float* x     = (const float*)d_in[0];
  const float* Wq    = (const float*)d_in[1];
  const float* bq    = (const float*)d_in[2];
  const float* Wk    = (const float*)d_in[3];
  const float* bk    = (const float*)d_in[4];
  const float* Wv    = (const float*)d_in[5];
  const float* bv    = (const float*)d_in[6];
  const float* Wo    = (const float*)d_in[7];
  const float* bo    = (const float*)d_in[8];
  const float* omega = (const float*)d_in[9];
  float* out = (float*)d_out;

  char* ws = (char*)d_ws;
  u16*   v      = (u16*)(ws);                           // 32 MB
  u16*   qb     = (u16*)(ws + 33554432ull);             // 32 MB
  u16*   kb     = (u16*)(ws + 67108864ull);             // 32 MB
  u16*   xb     = (u16*)(ws + 100663296ull);            // 32 MB (alias attn)
  u16*   attn   = xb;
  u16*   stateb = (u16*)(ws + 134217728ull);            // 64 MB
  float* ksum   = (float*)(ws + 201326592ull);          // 2 MB
  u16*   Wt     = (u16*)(ws + 203423744ull);            // 8 MB
  u16*   omb    = (u16*)(ws + 211812352ull);            // 32 KB
  float* nhq    = (float*)(ws + 211845120ull);          // 1 MB
  float* nhk    = (float*)(ws + 212893696ull);          // 1 MB -> 204 MB

  prep_k<<<3136, 256, 0, stream>>>(x, xb, Wq, Wk, Wv, Wo, Wt, omega, omb);
  mm3_k<<<dim3(1024, 3), 256, 0, stream>>>(xb, Wt, bq, bk, bv,
                                           qb, kb, v, nhq, nhk);
  kvstate_k<<<dim3(NSC / 4, BH_), 256, 0, stream>>>(kb, v, omb, nhk, stateb, ksum);
  scan_k<<<dim3(8, BH_), 256, 0, stream>>>(stateb, ksum);
  outchunk_k<<<BH_ * (NSC / 8), 512, 0, stream>>>(qb, kb, v, omb, stateb, ksum,
                                                  nhq, nhk, attn);
  mmo_k<<<1024, 256, 0, stream>>>(attn, Wt + 3145728ull, bo, out);
}

// Round 27
// 436.506 us; speedup vs baseline: 1.1288x; 1.0032x over previous
//
#include <hip/hip_runtime.h>
#include <hip/hip_bf16.h>

// FAVOR+ attention, MI355X. Round 27 (final): exact R24 best configuration.
//  - prep_k: merged convx/convw/convom, grid 17472 (R24-measured best).
//  - mm3_k: grid (1024,3), XCD-swizzled, nh' emitted (phi scale+ln16 folded).
//  - kvstate_k: MFMA, 4 superchunks/block.
//  - scan_k: parallel exclusive prefix (bf16 state, f32 ksum).
//  - outchunk_k: 8 superchunks/block, 2-half merged, 3 barriers/iter,
//    phi->reg via wave-private scratch, cross term direct-from-global.
//  - mmo_k: final GEMM.
// Best measured: 435.7 us (R24), absmax 0.0078125.
//
// Workspace (bytes), total 213,942,272 (~204 MB).

#define B_ 4
#define H_ 16
#define L_ 4096
#define D_ 64
#define M_ 256
#define DM_ 1024
#define BH_ 64
#define NSC 32            // superchunks per bh (SC = 128 tokens)

typedef unsigned int u32;
typedef unsigned short u16;
typedef __attribute__((ext_vector_type(8))) short bf16x8;
typedef __attribute__((ext_vector_type(4))) float f32x4;

static __device__ __forceinline__ float bf2f(u16 u) {
  return __uint_as_float(((u32)u) << 16);
}
static __device__ __forceinline__ u16 f2bf(float f) {
  u32 x = __float_as_uint(f);
  return (u16)((x + 0x7fffu + ((x >> 16) & 1u)) >> 16);   // RNE
}
#define MFMA16(a, b, c) __builtin_amdgcn_mfma_f32_16x16x32_bf16((a), (b), (c), 0, 0, 0)
#define LN16 2.772588722239781f

// ---------------- merged prep: convx | convw | convom ----------------------
__global__ __launch_bounds__(256) void prep_k(
    const float* __restrict__ x, u16* __restrict__ xb,
    const float* __restrict__ W0, const float* __restrict__ W1,
    const float* __restrict__ W2, const float* __restrict__ W3,
    u16* __restrict__ Wt, const float* __restrict__ om,
    u16* __restrict__ omb) {
  __shared__ u16 tt[64][66];
  const int bid = blockIdx.x, tid = threadIdx.x;
  if (bid < 16384) {
    const int i = bid * 256 + tid;
    float4 f = ((const float4*)x)[i];
    ushort4 u;
    u.x = f2bf(f.x); u.y = f2bf(f.y); u.z = f2bf(f.z); u.w = f2bf(f.w);
    ((ushort4*)xb)[i] = u;
  } else if (bid < 17408) {
    const int rem = bid - 16384;
    const int z = rem >> 8, r2 = rem & 255;
    const int k0 = (r2 >> 4) * 64, n0 = (r2 & 15) * 64;
    const float* W = (z == 0) ? W0 : (z == 1) ? W1 : (z == 2) ? W2 : W3;
    u16* o = Wt + (size_t)z * 1048576ull;
    const int r = tid >> 4, c4 = (tid & 15) << 2;
    for (int rr = r; rr < 64; rr += 16) {
      float4 w4 = *(const float4*)(W + (size_t)(k0 + rr) * DM_ + n0 + c4);
      tt[c4 + 0][rr] = f2bf(w4.x);
      tt[c4 + 1][rr] = f2bf(w4.y);
      tt[c4 + 2][rr] = f2bf(w4.z);
      tt[c4 + 3][rr] = f2bf(w4.w);
    }
    __syncthreads();
    for (int rr = r; rr < 64; rr += 16) {
      ushort4 u4;
      u4.x = tt[rr][c4 + 0];
      u4.y = tt[rr][c4 + 1];
      u4.z = tt[rr][c4 + 2];
      u4.w = tt[rr][c4 + 3];
      *(ushort4*)(o + (size_t)(n0 + rr) * DM_ + k0 + c4) = u4;
    }
  } else {
    const int i = (bid - 17408) * 256 + tid;
    omb[i] = f2bf(om[i] * 0.35355339059327373f);     // fold 64^-0.25
  }
}

// ---------------- merged projection GEMMs (q,k,v), head bf16 out -----------
// grid (1024, 3): y selects {Wq->qb(+nhq), Wk->kb(+nhk), Wv->v}
// nh' = 0.0625 * sum(bf2f(f2bf(v))^2) + ln16  (phi scale folded in)
__global__ __launch_bounds__(256) void mm3_k(
    const u16* __restrict__ A, const u16* __restrict__ Wt,
    const float* __restrict__ bq, const float* __restrict__ bk,
    const float* __restrict__ bv, u16* __restrict__ qb,
    u16* __restrict__ kb, u16* __restrict__ vb,
    float* __restrict__ nhq, float* __restrict__ nhk) {
  __shared__ u16 sA[128][64];   // 16 KB, XOR-swizzled 16B slots
  __shared__ u16 sB[128][64];   // 16 KB
  const int y = blockIdx.y;
  const u16* Bt = Wt + (size_t)y * 1048576ull;
  const float* bias = (y == 0) ? bq : (y == 1) ? bk : bv;
  u16* outp = (y == 0) ? qb : (y == 1) ? kb : vb;
  float* nhout = (y == 0) ? nhq : (y == 1) ? nhk : nullptr;
  const int tid = threadIdx.x, lane = tid & 63, w = tid >> 6;
  const int fr = lane & 15, fg = lane >> 4;
  const int wr = w >> 1, wc = w & 1;
  const int lb = ((blockIdx.x & 7) << 7) | (blockIdx.x >> 3);
  const int m0 = (lb >> 3) * 128, n0 = (lb & 7) * 128;
  const int srow = tid >> 3, sslot = tid & 7;   // +p*32 rows per pass
  f32x4 acc[4][4] = {};
  bf16x8 av[4], bv4[4];
#pragma unroll
  for (int p = 0; p < 4; ++p) {
    av[p]  = *(const bf16x8*)(A  + (size_t)(m0 + srow + p * 32) * DM_ + sslot * 8);
    bv4[p] = *(const bf16x8*)(Bt + (size_t)(n0 + srow + p * 32) * DM_ + sslot * 8);
  }
  for (int k0 = 0; k0 < DM_; k0 += 64) {
    __syncthreads();
#pragma unroll
    for (int p = 0; p < 4; ++p) {
      const int r = srow + p * 32;
      *(bf16x8*)&sA[r][(sslot ^ (r & 7)) * 8] = av[p];
      *(bf16x8*)&sB[r][(sslot ^ (r & 7)) * 8] = bv4[p];
    }
    if (k0 + 64 < DM_) {
#pragma unroll
      for (int p = 0; p < 4; ++p) {
        av[p]  = *(const bf16x8*)(A  + (size_t)(m0 + srow + p * 32) * DM_ + k0 + 64 + sslot * 8);
        bv4[p] = *(const bf16x8*)(Bt + (size_t)(n0 + srow + p * 32) * DM_ + k0 + 64 + sslot * 8);
      }
    }
    __syncthreads();
#pragma unroll
    for (int ks = 0; ks < 2; ++ks) {
      bf16x8 af[4], bf[4];
#pragma unroll
      for (int i = 0; i < 4; ++i) {
        const int r = wr * 64 + i * 16 + fr;
        af[i] = *(const bf16x8*)&sA[r][((ks * 4 + fg) ^ (r & 7)) * 8];
      }
#pragma unroll
      for (int j = 0; j < 4; ++j) {
        const int r = wc * 64 + j * 16 + fr;
        bf[j] = *(const bf16x8*)&sB[r][((ks * 4 + fg) ^ (r & 7)) * 8];
      }
#pragma unroll
      for (int i = 0; i < 4; ++i)
#pragma unroll
        for (int j = 0; j < 4; ++j)
          acc[i][j] = MFMA16(af[i], bf[j], acc[i][j]);
    }
  }
  const int m_blk = m0 + wr * 64, n_blk = n0 + wc * 64;
  float nhacc[4][4] = {};
#pragma unroll
  for (int j = 0; j < 4; ++j) {
    const int n = n_blk + j * 16 + fr;
    const float bi = bias[n];
    const int h = n >> 6, d = n & 63;
#pragma unroll
    for (int i = 0; i < 4; ++i) {
#pragma unroll
      for (int r = 0; r < 4; ++r) {
        const int m = m_blk + i * 16 + fg * 4 + r;
        const float val = acc[i][j][r] + bi;
        const int b = m >> 12, l = m & 4095;
        const u16 sv = f2bf(val);
        outp[((size_t)(b * H_ + h) * L_ + l) * D_ + d] = sv;
        const float rv = bf2f(sv);
        nhacc[i][r] += rv * rv;
      }
    }
  }
  if (nhout) {
    const int hh2 = n_blk >> 6;
#pragma unroll
    for (int i = 0; i < 4; ++i)
#pragma unroll
      for (int r = 0; r < 4; ++r) {
        float s = nhacc[i][r];
        s += __shfl_xor(s, 1, 64);
        s += __shfl_xor(s, 2, 64);
        s += __shfl_xor(s, 4, 64);
        s += __shfl_xor(s, 8, 64);
        if (fr == 0) {
          const int m = m_blk + i * 16 + fg * 4 + r;
          const int b = m >> 12, l = m & 4095;
          nhout[(size_t)(b * H_ + hh2) * L_ + l] = 0.0625f * s + LN16;
        }
      }
  }
}

// ---------------- final GEMM (attn bf16 -> f32 out), validated -------------
__global__ __launch_bounds__(256) void mmo_k(
    const u16* __restrict__ A, const u16* __restrict__ Bt,
    const float* __restrict__ bias, float* __restrict__ outp) {
  __shared__ u16 sA[128][64];
  __shared__ u16 sB[128][64];
  const int tid = threadIdx.x, lane = tid & 63, w = tid >> 6;
  const int fr = lane & 15, fg = lane >> 4;
  const int wr = w >> 1, wc = w & 1;
  const int lb = ((blockIdx.x & 7) << 7) | (blockIdx.x >> 3);
  const int m0 = (lb >> 3) * 128, n0 = (lb & 7) * 128;
  const int srow = tid >> 3, sslot = tid & 7;
  f32x4 acc[4][4] = {};
  bf16x8 av[4], bv[4];
#pragma unroll
  for (int p = 0; p < 4; ++p) {
    av[p] = *(const bf16x8*)(A  + (size_t)(m0 + srow + p * 32) * DM_ + sslot * 8);
    bv[p] = *(const bf16x8*)(Bt + (size_t)(n0 + srow + p * 32) * DM_ + sslot * 8);
  }
  for (int k0 = 0; k0 < DM_; k0 += 64) {
    __syncthreads();
#pragma unroll
    for (int p = 0; p < 4; ++p) {
      const int r = srow + p * 32;
      *(bf16x8*)&sA[r][(sslot ^ (r & 7)) * 8] = av[p];
      *(bf16x8*)&sB[r][(sslot ^ (r & 7)) * 8] = bv[p];
    }
    if (k0 + 64 < DM_) {
#pragma unroll
      for (int p = 0; p < 4; ++p) {
        av[p] = *(const bf16x8*)(A  + (size_t)(m0 + srow + p * 32) * DM_ + k0 + 64 + sslot * 8);
        bv[p] = *(const bf16x8*)(Bt + (size_t)(n0 + srow + p * 32) * DM_ + k0 + 64 + sslot * 8);
      }
    }
    __syncthreads();
#pragma unroll
    for (int ks = 0; ks < 2; ++ks) {
      bf16x8 af[4], bf[4];
#pragma unroll
      for (int i = 0; i < 4; ++i) {
        const int r = wr * 64 + i * 16 + fr;
        af[i] = *(const bf16x8*)&sA[r][((ks * 4 + fg) ^ (r & 7)) * 8];
      }
#pragma unroll
      for (int j = 0; j < 4; ++j) {
        const int r = wc * 64 + j * 16 + fr;
        bf[j] = *(const bf16x8*)&sB[r][((ks * 4 + fg) ^ (r & 7)) * 8];
      }
#pragma unroll
      for (int i = 0; i < 4; ++i)
#pragma unroll
        for (int j = 0; j < 4; ++j)
          acc[i][j] = MFMA16(af[i], bf[j], acc[i][j]);
    }
  }
  const int m_blk = m0 + wr * 64, n_blk = n0 + wc * 64;
#pragma unroll
  for (int j = 0; j < 4; ++j) {
    const int n = n_blk + j * 16 + fr;
    const float bi = bias[n];
#pragma unroll
    for (int i = 0; i < 4; ++i)
#pragma unroll
      for (int r = 0; r < 4; ++r) {
        const int m = m_blk + i * 16 + fg * 4 + r;
        outp[(size_t)m * DM_ + n] = acc[i][j][r] + bi;
      }
  }
}

// ---------------- kvstate (MFMA, SC=128, 4 superchunks/block) --------------
__global__ __launch_bounds__(256) void kvstate_k(
    const u16* __restrict__ k, const u16* __restrict__ v,
    const u16* __restrict__ omb, const float* __restrict__ nhk,
    u16* __restrict__ stateb, float* __restrict__ ksum) {
  __shared__ u16 sPhi[256][72];
  __shared__ u16 sVt[64][72];
  const int tid = threadIdx.x, lane = tid & 63, w = tid >> 6;
  const int fr = lane & 15, fg = lane >> 4;
  const int bh = blockIdx.y;

  bf16x8 ones;
#pragma unroll
  for (int e = 0; e < 8; ++e) ones[e] = (short)0x3F80;

#pragma unroll 1
  for (int isc = 0; isc < 4; ++isc) {
    const int sc = blockIdx.x * 4 + isc;
    const size_t base_l = (size_t)bh * L_ + (size_t)sc * 128;

    f32x4 kvacc[4][4] = {};
    f32x4 ksacc[4] = {};

    for (int sub = 0; sub < 2; ++sub) {
      const size_t tl = base_l + sub * 64;
      const u16* kg = k + tl * 64;
      __syncthreads();   // fences prior sPhi/sVt readers (incl. prev isc)
      {
        const u16* vp = v + (tl + lane) * 64 + w * 16;
        bf16x8 v0 = *(const bf16x8*)(vp);
        bf16x8 v1 = *(const bf16x8*)(vp + 8);
#pragma unroll
        for (int e = 0; e < 8; ++e) sVt[w * 16 + e][lane] = (u16)v0[e];
#pragma unroll
        for (int e = 0; e < 8; ++e) sVt[w * 16 + 8 + e][lane] = (u16)v1[e];
      }
      float nhr[4];
#pragma unroll
      for (int tt = 0; tt < 4; ++tt) nhr[tt] = nhk[tl + tt * 16 + fr];
#pragma unroll
      for (int mi = 0; mi < 4; ++mi) {
        const int m0 = (w << 6) + mi * 16;
        const bf16x8 a0 = *(const bf16x8*)(omb + (m0 + fr) * 64 + fg * 8);
        const bf16x8 a1 = *(const bf16x8*)(omb + (m0 + fr) * 64 + 32 + fg * 8);
#pragma unroll
        for (int tt = 0; tt < 4; ++tt) {
          const bf16x8 b0 = *(const bf16x8*)(kg + (tt * 16 + fr) * 64 + fg * 8);
          const bf16x8 b1 = *(const bf16x8*)(kg + (tt * 16 + fr) * 64 + 32 + fg * 8);
          f32x4 acc = {0.f, 0.f, 0.f, 0.f};
          acc = MFMA16(a0, b0, acc);
          acc = MFMA16(a1, b1, acc);
          const float nhv = nhr[tt];
#pragma unroll
          for (int r = 0; r < 4; ++r)
            sPhi[m0 + fg * 4 + r][tt * 16 + fr] = f2bf(__expf(acc[r] - nhv));
        }
      }
      __syncthreads();
#pragma unroll
      for (int mi = 0; mi < 4; ++mi) {
        const int m0 = (w << 6) + mi * 16;
        const bf16x8 pb0 = *(const bf16x8*)&sPhi[m0 + fr][fg * 8];
        const bf16x8 pb1 = *(const bf16x8*)&sPhi[m0 + fr][32 + fg * 8];
        ksacc[mi] = MFMA16(pb0, ones, ksacc[mi]);
        ksacc[mi] = MFMA16(pb1, ones, ksacc[mi]);
#pragma unroll
        for (int dj = 0; dj < 4; ++dj) {
          const bf16x8 va0 = *(const bf16x8*)&sVt[dj * 16 + fr][fg * 8];
          const bf16x8 va1 = *(const bf16x8*)&sVt[dj * 16 + fr][32 + fg * 8];
          kvacc[mi][dj] = MFMA16(va0, pb0, kvacc[mi][dj]);
          kvacc[mi][dj] = MFMA16(va1, pb1, kvacc[mi][dj]);
        }
      }
    }
    // state bf16 [d][m]; ksum f32
    u16* stb = stateb + (size_t)(bh * NSC + sc) * (M_ * D_);
    float* ksp = ksum + (size_t)(bh * NSC + sc) * M_;
#pragma unroll
    for (int mi = 0; mi < 4; ++mi) {
      const int m = (w << 6) + mi * 16 + fr;
#pragma unroll
      for (int dj = 0; dj < 4; ++dj)
#pragma unroll
        for (int r = 0; r < 4; ++r)
          stb[(size_t)(dj * 16 + fg * 4 + r) * M_ + m] = f2bf(kvacc[mi][dj][r]);
      if (fr == 0) {
#pragma unroll
        for (int r = 0; r < 4; ++r)
          ksp[(w << 6) + mi * 16 + fg * 4 + r] = ksacc[mi][r];
      }
    }
  }
}

// ---------------- exclusive prefix over superchunks (bf16 state) -----------
__global__ __launch_bounds__(256) void scan_k(u16* __restrict__ stateb,
                                              float* __restrict__ ksum) {
  const int bh = blockIdx.y;
  u16* sb = stateb + (size_t)bh * NSC * (M_ * D_);
  const int base = blockIdx.x * 2048 + threadIdx.x * 8;
  float run[8] = {};
  for (int cc = 0; cc < NSC; ++cc) {
    u16* st = sb + (size_t)cc * (M_ * D_) + base;
    ushort4 t0 = *(ushort4*)st;
    ushort4 t1 = *(ushort4*)(st + 4);
    ushort4 w0, w1;
    w0.x = f2bf(run[0]); w0.y = f2bf(run[1]); w0.z = f2bf(run[2]); w0.w = f2bf(run[3]);
    w1.x = f2bf(run[4]); w1.y = f2bf(run[5]); w1.z = f2bf(run[6]); w1.w = f2bf(run[7]);
    *(ushort4*)st = w0;
    *(ushort4*)(st + 4) = w1;
    run[0] += bf2f(t0.x); run[1] += bf2f(t0.y); run[2] += bf2f(t0.z); run[3] += bf2f(t0.w);
    run[4] += bf2f(t1.x); run[5] += bf2f(t1.y); run[6] += bf2f(t1.z); run[7] += bf2f(t1.w);
  }
  if (blockIdx.x == 0) {           // ksum f32 in-place exclusive prefix
    float rk = 0.f;
    for (int cc = 0; cc < NSC; ++cc) {
      float* p = ksum + (size_t)(bh * NSC + cc) * M_ + threadIdx.x;
      const float t = *p;
      *p = rk;
      rk += t;
    }
  }
}

// ---------------- outchunk helpers -----------------------------------------
// phi quadrant from PRELOADED x-frags: writes ONLY rows of band wb
static __device__ __forceinline__ void phi_quad_r(
    bf16x8 a0, bf16x8 a1, const u16* __restrict__ ombq,
    u16* __restrict__ dst, int dstride, const float* nhv,
    int wb, int lane) {
  const int fr = lane & 15, fg = lane >> 4;
  const int tband = wb * 16;
#pragma unroll
  for (int j = 0; j < 4; ++j) {
    const bf16x8 b0 = *(const bf16x8*)(ombq + (j * 16 + fr) * 64 + fg * 8);
    const bf16x8 b1 = *(const bf16x8*)(ombq + (j * 16 + fr) * 64 + 32 + fg * 8);
    f32x4 acc = {0.f, 0.f, 0.f, 0.f};
    acc = MFMA16(a0, b0, acc);
    acc = MFMA16(a1, b1, acc);
#pragma unroll
    for (int r = 0; r < 4; ++r) {
      const int t = tband + fg * 4 + r;
      dst[t * dstride + j * 16 + fr] = f2bf(__expf(acc[r] - nhv[r]));
    }
  }
}

// ---------------- outchunk: 8 superchunks/block (R22/R24 structure) --------
__global__ __launch_bounds__(512, 2) void outchunk_k(
    const u16* __restrict__ q, const u16* __restrict__ kk,
    const u16* __restrict__ v, const u16* __restrict__ omb,
    const u16* __restrict__ stateb, const float* __restrict__ ksum,
    const float* __restrict__ nhq, const float* __restrict__ nhk,
    u16* __restrict__ attn) {
  __shared__ u16 sKa[64][264];    // Kp chunk0 (h0-produced)
  __shared__ u16 sKb[64][264];    // Kp chunk1 (h1-produced)
  __shared__ u16 sS0[64][72];     // h0 q-scratch / h0 masked S
  __shared__ u16 sS1[64][72];     // h1 q-scratch / h1 masked S
  __shared__ u16 sB1[64][72];     // vT chunk0 (h0-staged)
  __shared__ u16 sB2[64][72];     // vT chunk1 (h1-staged)
  __shared__ float ksum_l[256];   // total 105,472 B -> 1 block/CU
  const int tid = threadIdx.x, lane = tid & 63, w = tid >> 6;
  const int h = w >> 2, wl = w & 3;
  const int fr = lane & 15, fg = lane >> 4;
  const int bh = blockIdx.x >> 2, scp = blockIdx.x & 3;

#pragma unroll 1
  for (int it = 0; it < 8; ++it) {
    const int sc = scp * 8 + it;
    const size_t base_l = (size_t)bh * L_ + (size_t)sc * 128;
    const size_t tokq = base_l + (size_t)h * 64;
    const u16* qg = q + tokq * 64;
    const u16* stgb = stateb + (size_t)(bh * NSC + sc) * (M_ * D_);  // [d][m]
    const float* ksg = ksum + (size_t)(bh * NSC + sc) * M_;

    if (tid < 256) ksum_l[tid] = ksg[tid];

    // early v loads: half h loads its own chunk's v
    bf16x8 ev0, ev1;
    {
      const u16* vp = v + (base_l + (size_t)h * 64 + lane) * 64 + wl * 16;
      ev0 = *(const bf16x8*)(vp);
      ev1 = *(const bf16x8*)(vp + 8);
    }

    // phi(k): half h fills its chunk's Kp entirely (own rows, no syncs);
    // x-row loaded once (phi_quad_r).
    u16* kdst = (h == 0) ? &sKa[0][0] : &sKb[0][0];
    {
      const size_t ktokh = base_l + (size_t)h * 64;
      const u16* kgh = kk + ktokh * 64;
      float nhkh[4];
#pragma unroll
      for (int r = 0; r < 4; ++r) nhkh[r] = nhk[ktokh + wl * 16 + fg * 4 + r];
      const bf16x8 xk0 = *(const bf16x8*)(kgh + (wl * 16 + fr) * 64 + fg * 8);
      const bf16x8 xk1 = *(const bf16x8*)(kgh + (wl * 16 + fr) * 64 + 32 + fg * 8);
#pragma unroll
      for (int mq = 0; mq < 4; ++mq)
        phi_quad_r(xk0, xk1, omb + mq * 4096, kdst + mq * 64, 264, nhkh, wl, lane);
    }

    // phi(q) -> regs via own half's S buffer as scratch (wave-private rows);
    // cross term fused; x-row loaded once.
    float nhq4[4];
#pragma unroll
    for (int r = 0; r < 4; ++r) nhq4[r] = nhq[tokq + wl * 16 + fg * 4 + r];
    u16* myscr = (h == 0) ? &sS0[0][0] : &sS1[0][0];
    const bf16x8 xq0 = *(const bf16x8*)(qg + (wl * 16 + fr) * 64 + fg * 8);
    const bf16x8 xq1 = *(const bf16x8*)(qg + (wl * 16 + fr) * 64 + 32 + fg * 8);
    bf16x8 qa0[2], qa1[2], qa2[2], qa3[2];
    f32x4 oacc[4] = {};
#define QPHASE(MQ, QA)                                                          \
    {                                                                           \
      bf16x8 b0r[4], b1r[4];                                                    \
      _Pragma("unroll")                                                         \
      for (int j = 0; j < 4; ++j) {                                             \
        b0r[j] = *(const bf16x8*)(stgb + (size_t)(j * 16 + fr) * M_ + MQ * 64 + fg * 8);      \
        b1r[j] = *(const bf16x8*)(stgb + (size_t)(j * 16 + fr) * M_ + MQ * 64 + 32 + fg * 8); \
      }                                                                         \
      phi_quad_r(xq0, xq1, omb + MQ * 4096, myscr, 72, nhq4, wl, lane);         \
      QA[0] = *(const bf16x8*)(myscr + (wl * 16 + fr) * 72 + fg * 8);           \
      QA[1] = *(const bf16x8*)(myscr + (wl * 16 + fr) * 72 + 32 + fg * 8);      \
      __builtin_amdgcn_s_setprio(1);                                            \
      _Pragma("unroll")                                                         \
      for (int j = 0; j < 4; ++j) {                                             \
        oacc[j] = MFMA16(QA[0], b0r[j], oacc[j]);                               \
        oacc[j] = MFMA16(QA[1], b1r[j], oacc[j]);                               \
      }                                                                         \
      __builtin_amdgcn_s_setprio(0);                                            \
    }
    QPHASE(0, qa0)
    QPHASE(1, qa1)
    QPHASE(2, qa2)
    QPHASE(3, qa3)
#undef QPHASE
    __syncthreads();   // BAR K: ksum_l + full Kp (sKa/sKb) visible to all

    // den-ksum from register frags
    float denk = 0.f;
#pragma unroll
    for (int e = 0; e < 8; ++e) {
      denk += bf2f((u16)qa0[0][e]) * ksum_l[0   + fg * 8 + e]
            + bf2f((u16)qa0[1][e]) * ksum_l[32  + fg * 8 + e]
            + bf2f((u16)qa1[0][e]) * ksum_l[64  + fg * 8 + e]
            + bf2f((u16)qa1[1][e]) * ksum_l[96  + fg * 8 + e]
            + bf2f((u16)qa2[0][e]) * ksum_l[128 + fg * 8 + e]
            + bf2f((u16)qa2[1][e]) * ksum_l[160 + fg * 8 + e]
            + bf2f((u16)qa3[0][e]) * ksum_l[192 + fg * 8 + e]
            + bf2f((u16)qa3[1][e]) * ksum_l[224 + fg * 8 + e];
    }
    denk += __shfl_xor(denk, 16, 64);
    denk += __shfl_xor(denk, 32, 64);

    // ---- S chunk0 (all waves): 32 MFMA, B-frags from sKa
    float dS[4] = {0.f, 0.f, 0.f, 0.f};
    {
      f32x4 sacc[4] = {};
      __builtin_amdgcn_s_setprio(1);
#define SPH0(MQ, QA)                                                            \
      _Pragma("unroll")                                                         \
      for (int j = 0; j < 4; ++j) {                                             \
        const bf16x8 b0 = *(const bf16x8*)&sKa[j * 16 + fr][MQ * 64 + fg * 8];  \
        const bf16x8 b1 = *(const bf16x8*)&sKa[j * 16 + fr][MQ * 64 + 32 + fg * 8]; \
        sacc[j] = MFMA16(QA[0], b0, sacc[j]);                                   \
        sacc[j] = MFMA16(QA[1], b1, sacc[j]);                                   \
      }
      SPH0(0, qa0)
      SPH0(1, qa1)
      SPH0(2, qa2)
      SPH0(3, qa3)
#undef SPH0
      __builtin_amdgcn_s_setprio(0);
      u16 (*sSo)[72] = (h == 0) ? sS0 : sS1;
#pragma unroll
      for (int j = 0; j < 4; ++j)
#pragma unroll
        for (int r = 0; r < 4; ++r) {
          const int ss = j * 16 + fr, t = wl * 16 + fg * 4 + r;
          float val = sacc[j][r];
          if (h == 0 && ss > t) val = 0.f;
          const u16 vb = f2bf(val);
          sSo[t][ss] = vb;
          dS[r] += bf2f(vb);
        }
    }
    // vT staging: h0 -> sB1 (chunk0), h1 -> sB2 (chunk1)
    {
      u16 (*sBo)[72] = (h == 0) ? sB1 : sB2;
#pragma unroll
      for (int e = 0; e < 8; ++e) sBo[wl * 16 + e][lane] = (u16)ev0[e];
#pragma unroll
      for (int e = 0; e < 8; ++e) sBo[wl * 16 + 8 + e][lane] = (u16)ev1[e];
    }
    __syncthreads();   // BAR F0: sS0/sS1 + sB1/sB2 visible

    // ---- S@V chunk0 (all waves): A = own masked S (own band), B = sB1
    {
      const u16 (*sSo)[72] = (h == 0) ? sS0 : sS1;
      const bf16x8 a0 = *(const bf16x8*)&sSo[wl * 16 + fr][fg * 8];
      const bf16x8 a1 = *(const bf16x8*)&sSo[wl * 16 + fr][32 + fg * 8];
      __builtin_amdgcn_s_setprio(1);
#pragma unroll
      for (int j = 0; j < 4; ++j) {
        const bf16x8 b0 = *(const bf16x8*)&sB1[j * 16 + fr][fg * 8];
        const bf16x8 b1 = *(const bf16x8*)&sB1[j * 16 + fr][32 + fg * 8];
        oacc[j] = MFMA16(a0, b0, oacc[j]);
        oacc[j] = MFMA16(a1, b1, oacc[j]);
      }
      __builtin_amdgcn_s_setprio(0);
    }

    // ---- h1 only: S chunk1 (sKb) -> masked sS1 -> S@V chunk1 (sB2)
    if (h == 1) {
      f32x4 sacc[4] = {};
      __builtin_amdgcn_s_setprio(1);
#define SPH1(MQ, QA)                                                            \
      _Pragma("unroll")                                                         \
      for (int j = 0; j < 4; ++j) {                                             \
        const bf16x8 b0 = *(const bf16x8*)&sKb[j * 16 + fr][MQ * 64 + fg * 8];  \
        const bf16x8 b1 = *(const bf16x8*)&sKb[j * 16 + fr][MQ * 64 + 32 + fg * 8]; \
        sacc[j] = MFMA16(QA[0], b0, sacc[j]);                                   \
        sacc[j] = MFMA16(QA[1], b1, sacc[j]);                                   \
      }
      SPH1(0, qa0)
      SPH1(1, qa1)
      SPH1(2, qa2)
      SPH1(3, qa3)
#undef SPH1
      __builtin_amdgcn_s_setprio(0);
#pragma unroll
      for (int j = 0; j < 4; ++j)
#pragma unroll
        for (int r = 0; r < 4; ++r) {
          const int ss = j * 16 + fr, t = wl * 16 + fg * 4 + r;
          float val = sacc[j][r];
          if (ss > t) val = 0.f;         // diag (s == h == 1)
          const u16 vb = f2bf(val);
          sS1[t][ss] = vb;
          dS[r] += bf2f(vb);
        }
      {
        const bf16x8 a0 = *(const bf16x8*)&sS1[wl * 16 + fr][fg * 8];
        const bf16x8 a1 = *(const bf16x8*)&sS1[wl * 16 + fr][32 + fg * 8];
        __builtin_amdgcn_s_setprio(1);
#pragma unroll
        for (int j = 0; j < 4; ++j) {
          const bf16x8 b0 = *(const bf16x8*)&sB2[j * 16 + fr][fg * 8];
          const bf16x8 b1 = *(const bf16x8*)&sB2[j * 16 + fr][32 + fg * 8];
          oacc[j] = MFMA16(a0, b0, oacc[j]);
          oacc[j] = MFMA16(a1, b1, oacc[j]);
        }
        __builtin_amdgcn_s_setprio(0);
      }
    }

    // den: reduce dS over fr lanes; combine with denk via shfl
#pragma unroll
    for (int m2 = 1; m2 <= 8; m2 <<= 1) {
#pragma unroll
      for (int r = 0; r < 4; ++r) dS[r] += __shfl_xor(dS[r], m2, 64);
    }
    const int b = bh >> 4, hh = bh & 15;
#pragma unroll
    for (int r = 0; r < 4; ++r) {
      const float dk = __shfl(denk, fg * 4 + r, 64);   // token wl*16+fg*4+r
      const float rinv = 1.0f / (dk + dS[r] + 1e-6f);
      const int t = wl * 16 + fg * 4 + r;
      const int l = sc * 128 + h * 64 + t;
#pragma unroll
      for (int j = 0; j < 4; ++j) {
        const int d = j * 16 + fr;
        attn[((size_t)b * L_ + l) * DM_ + hh * 64 + d] = f2bf(oacc[j][r] * rinv);
      }
    }
    __syncthreads();   // BAR E: full fence before next superchunk's reuse
  }
}

extern "C" void kernel_launch(void* const* d_in, const int* in_sizes, int n_in,
                              void* d_out, int out_size, void* d_ws, size_t ws_size,
                              hipStream_t stream) {
  const float* x     = (const float*)d_in[0];
  const float* Wq    = (const float*)d_in[1];
  const float* bq    = (const float*)d_in[2];
  const float* Wk    = (const float*)d_in[3];
  const float* bk    = (const float*)d_in[4];
  const float* Wv    = (const float*)d_in[5];
  const float* bv    = (const float*)d_in[6];
  const float* Wo    = (const float*)d_in[7];
  const float* bo    = (const float*)d_in[8];
  const float* omega = (const float*)d_in[9];
  float* out = (float*)d_out;

  char* ws = (char*)d_ws;
  u16*   v      = (u16*)(ws);                           // 32 MB
  u16*   qb     = (u16*)(ws + 33554432ull);             // 32 MB
  u16*   kb     = (u16*)(ws + 67108864ull);             // 32 MB
  u16*   xb     = (u16*)(ws + 100663296ull);            // 32 MB (alias attn)
  u16*   attn   = xb;
  u16*   stateb = (u16*)(ws + 134217728ull);            // 64 MB
  float* ksum   = (float*)(ws + 201326592ull);          // 2 MB
  u16*   Wt     = (u16*)(ws + 203423744ull);            // 8 MB
  u16*   omb    = (u16*)(ws + 211812352ull);            // 32 KB
  float* nhq    = (float*)(ws + 211845120ull);          // 1 MB
  float* nhk    = (float*)(ws + 212893696ull);          // 1 MB -> 204 MB

  prep_k<<<17472, 256, 0, stream>>>(x, xb, Wq, Wk, Wv, Wo, Wt, omega, omb);
  mm3_k<<<dim3(1024, 3), 256, 0, stream>>>(xb, Wt, bq, bk, bv,
                                           qb, kb, v, nhq, nhk);
  kvstate_k<<<dim3(NSC / 4, BH_), 256, 0, stream>>>(kb, v, omb, nhk, stateb, ksum);
  scan_k<<<dim3(8, BH_), 256, 0, stream>>>(stateb, ksum);
  outchunk_k<<<BH_ * (NSC / 8), 512, 0, stream>>>(qb, kb, v, omb, stateb, ksum,
                                                  nhq, nhk, attn);
  mmo_k<<<1024, 256, 0, stream>>>(attn, Wt + 3145728ull, bo, out);
}